// Round 7
// baseline (548.856 us; speedup 1.0000x reference)
//
#include <hip/hip_runtime.h>
#include <hip/hip_bf16.h>
#include <hip/hip_fp16.h>

// LSTM: B=512, T=512, I=128, H=256, gates G=4H=1024 (PyTorch i,f,g,o order).
// Fused pipeline: per chunk c, ONE launch runs lstm(chunk c) on blocks 0-127
// (R=4 batch rows/block, w_hh i8 pinned in 128 VGPRs/thread, M-rows {0,4,8,12})
// concurrently with xgemm(chunk c+1) on blocks 128-255. Kernel boundary = dep.
// Round-7 fix: launch_bounds(512) [was (512,2) -> 128-VGPR cap -> weights
// spilled & re-loaded each step] + asm pin on wf + even/odd MFMA split.

typedef __attribute__((ext_vector_type(4))) float f32x4;
typedef __attribute__((ext_vector_type(8))) _Float16 f16x8;
typedef __attribute__((ext_vector_type(4))) unsigned int u32x4;
typedef __attribute__((ext_vector_type(4))) int i32x4;

static __device__ __forceinline__ float h2f(unsigned short u) {
  return (float)__builtin_bit_cast(_Float16, u);
}
static __device__ __forceinline__ unsigned short f2h(float f) {
  return __builtin_bit_cast(unsigned short, (_Float16)f);
}
static __device__ __forceinline__ float fast_sigmoid(float x) {
  return __builtin_amdgcn_rcpf(1.0f + __builtin_amdgcn_exp2f(-1.44269504f * x));
}
static __device__ __forceinline__ float fast_tanh(float x) {
  return 1.0f - 2.0f * __builtin_amdgcn_rcpf(1.0f + __builtin_amdgcn_exp2f(2.88539008f * x));
}

// ---------------------------------------------------------------- small utils
__global__ void zero2(float* p) { if (threadIdx.x < 2) p[threadIdx.x] = 0.f; }

__global__ void absmax_red(const float* __restrict__ src, int n, float* __restrict__ out) {
  __shared__ float s[256];
  float m = 0.f;
  for (int i = blockIdx.x * 256 + threadIdx.x; i < n; i += gridDim.x * 256)
    m = fmaxf(m, fabsf(src[i]));
  s[threadIdx.x] = m; __syncthreads();
  for (int w = 128; w > 0; w >>= 1) {
    if (threadIdx.x < w) s[threadIdx.x] = fmaxf(s[threadIdx.x], s[threadIdx.x + w]);
    __syncthreads();
  }
  if (threadIdx.x == 0) atomicMax((int*)out, __float_as_int(s[0]));
}

__global__ void quant_w(const float* __restrict__ w, const float* __restrict__ scales,
                        signed char* __restrict__ wq, int n) {
  int i = blockIdx.x * 256 + threadIdx.x;
  if (i < n) {
    float inv = 127.0f / scales[0];
    int q = (int)rintf(w[i] * inv);
    q = max(-127, min(127, q));
    wq[i] = (signed char)q;
  }
}

// w_ih cast with gate-row interleave: dst row q <- src row (q&3)*256 + (q>>2)
__global__ void wperm_cast(const float* __restrict__ w, unsigned short* __restrict__ dst) {
  int i = (blockIdx.x * 256 + threadIdx.x) * 4;  // over 131072
  if (i < 131072) {
    int q = i >> 7, k = i & 127;
    int p = (q & 3) * 256 + (q >> 2);
    f32x4 v = *(const f32x4*)(w + p * 128 + k);
    ushort4 pk;
    pk.x = f2h(v[0]); pk.y = f2h(v[1]); pk.z = f2h(v[2]); pk.w = f2h(v[3]);
    *(ushort4*)(dst + i) = pk;
  }
}

__global__ void bias_perm(const float* __restrict__ bi, const float* __restrict__ bh,
                          float* __restrict__ bc) {
  int q = blockIdx.x * 256 + threadIdx.x;  // 1024
  int p = (q & 3) * 256 + (q >> 2);
  bc[q] = bi[p] + bh[p];
}

__global__ void state_init(const float* __restrict__ h0, const float* __restrict__ c0,
                           const float* __restrict__ scales,
                           signed char* __restrict__ hst, float* __restrict__ cst) {
  int i = blockIdx.x * 256 + threadIdx.x;  // grid 512 -> 131072
  float inv = 127.0f / scales[1];
  int q = (int)rintf(h0[i] * inv);
  q = max(-127, min(127, q));
  hst[i] = (signed char)q;
  cst[i] = c0[i];
}

// ---------------------------------------------------------------- prologue gemm
__global__ __launch_bounds__(256) void xgemm(
    const float* __restrict__ x, const unsigned short* __restrict__ wih,
    const float* __restrict__ bconv,
    unsigned short* __restrict__ xg, int t0, int tclog) {
  __shared__ unsigned short Ash[128 * 128];
  __shared__ unsigned short Bsh[128 * 128];

  const int tid  = threadIdx.x;
  const int lane = tid & 63;
  const int wv   = tid >> 6;
  const int c16  = lane & 15;
  const int gq   = lane >> 4;
  const long m0  = (long)blockIdx.x * 128;
  const int tcm  = (1 << tclog) - 1;

#pragma unroll
  for (int i = 0; i < 16; ++i) {
    int fidx = (i * 256 + tid) * 4;
    int row = fidx >> 7, k = fidx & 127;
    long cr = m0 + row;
    long b  = cr >> tclog;
    long tl = cr & tcm;
    f32x4 v = *(const f32x4*)(x + ((size_t)b * 512 + t0 + tl) * 128 + k);
    ushort4 pk;
    pk.x = f2h(v[0]); pk.y = f2h(v[1]); pk.z = f2h(v[2]); pk.w = f2h(v[3]);
    int byte = (row * 256 + k * 2) ^ ((row & 7) << 4);
    *(ushort4*)((char*)Ash + byte) = pk;
  }

  const int mh = (wv >> 1) * 64;
  const int nh = (wv & 1) * 64;

  for (int nc = 0; nc < 8; ++nc) {
    __syncthreads();
    {
      const char* wb = (const char*)(wih + nc * 128 * 128);
#pragma unroll
      for (int i = 0; i < 8; ++i) {
        int idx16 = i * 256 + tid;
        int row = idx16 >> 4, ch = idx16 & 15;
        int srcoff = row * 256 + ((ch * 16) ^ ((row & 7) << 4));
        u32x4 v = *(const u32x4*)(wb + srcoff);
        *(u32x4*)((char*)Bsh + idx16 * 16) = v;
      }
    }
    __syncthreads();

    float bias_v[4];
#pragma unroll
    for (int nt = 0; nt < 4; ++nt)
      bias_v[nt] = bconv[nc * 128 + nh + nt * 16 + c16];

    f16x8 af[4][4], bfr[4][4];
#pragma unroll
    for (int sm = 0; sm < 4; ++sm)
#pragma unroll
      for (int kt = 0; kt < 4; ++kt) {
        int m = mh + sm * 16 + c16;
        int byte = (m * 256 + (kt * 32 + gq * 8) * 2) ^ ((m & 7) << 4);
        af[sm][kt] = __builtin_bit_cast(f16x8, *(const u32x4*)((const char*)Ash + byte));
      }
#pragma unroll
    for (int nt = 0; nt < 4; ++nt)
#pragma unroll
      for (int kt = 0; kt < 4; ++kt) {
        int n = nh + nt * 16 + c16;
        int byte = (n * 256 + (kt * 32 + gq * 8) * 2) ^ ((n & 7) << 4);
        bfr[nt][kt] = __builtin_bit_cast(f16x8, *(const u32x4*)((const char*)Bsh + byte));
      }

    f32x4 acc[4][4];
#pragma unroll
    for (int sm = 0; sm < 4; ++sm)
#pragma unroll
      for (int nt = 0; nt < 4; ++nt) { f32x4 z = {0.f, 0.f, 0.f, 0.f}; acc[sm][nt] = z; }
#pragma unroll
    for (int sm = 0; sm < 4; ++sm)
#pragma unroll
      for (int nt = 0; nt < 4; ++nt)
#pragma unroll
        for (int kt = 0; kt < 4; ++kt)
          acc[sm][nt] = __builtin_amdgcn_mfma_f32_16x16x32_f16(af[sm][kt], bfr[nt][kt], acc[sm][nt], 0, 0, 0);

#pragma unroll
    for (int sm = 0; sm < 4; ++sm)
#pragma unroll
      for (int nt = 0; nt < 4; ++nt) {
        long row = m0 + mh + sm * 16 + gq * 4;
        int gcol = nc * 128 + nh + nt * 16 + c16;
#pragma unroll
        for (int r = 0; r < 4; ++r)
          xg[(size_t)(row + r) * 1024 + gcol] = f2h(acc[sm][nt][r] + bias_v[nt]);
      }
  }
}

// ---------------------------------------------------------------- fused kernel
// blocks 0-127: lstm chunk c (4 batch rows each). blocks 128-255: xgemm c+1.
__global__ __launch_bounds__(512) void fused_chunk(
    const unsigned short* __restrict__ xgc, const signed char* __restrict__ wq,
    const float* __restrict__ scales, signed char* __restrict__ hst,
    float* __restrict__ cst, float* __restrict__ out, int Tc, int first, int last,
    const float* __restrict__ x, const unsigned short* __restrict__ wih,
    const float* __restrict__ bconv, unsigned short* __restrict__ xgn,
    int t0n, int tclog, int do_x) {
  __shared__ char smem[65536];

  const int tid  = threadIdx.x;
  const int lane = tid & 63;
  const int wv   = tid >> 6;      // 0..7
  const int c16  = lane & 15;
  const int gq   = lane >> 4;     // 0..3

  if (blockIdx.x < 128) {
    // ------------------------------ LSTM: 4 batch rows, M-rows {0,4,8,12}
    signed char (*hb)[1280] = (signed char (*)[1280])smem;  // [buf][4 rows x 320B]
    const int b0 = blockIdx.x * 4;

    // weights: n = (nt>>1)*256 + wv*32 + (nt&1)*16 + c16 ; k = kt*64 + gq*16
    i32x4 wf[8][4];
#pragma unroll
    for (int nt = 0; nt < 8; ++nt)
#pragma unroll
      for (int kt = 0; kt < 4; ++kt) {
        int n = (nt >> 1) * 256 + wv * 32 + (nt & 1) * 16 + c16;
        wf[nt][kt] = *(const i32x4*)(wq + n * 256 + kt * 64 + gq * 16);
      }
    // pin the weight fragments in VGPRs (defeat spill/remat heuristics)
#pragma unroll
    for (int nt = 0; nt < 8; ++nt)
#pragma unroll
      for (int kt = 0; kt < 4; ++kt)
        asm volatile("" : "+v"(wf[nt][kt]));

    // init hb[0]: rows 0..3 (stride 320B), cols 0..255
    for (int i = tid; i < 1024; i += 512) {
      int row = i >> 8, cc = i & 255;
      hb[0][row * 320 + cc] = hst[(b0 + row) * 256 + cc];
    }

    const int col = wv * 32 + c16;     // output cols: col and col+16; row = gq
    float cv0 = cst[(b0 + gq) * 256 + col];
    float cv1 = cst[(b0 + gq) * 256 + col + 16];

    const float sw   = scales[0] * (1.0f / 127.0f);
    const float facR = sw * (1.0f / 127.0f);
    const float fac0 = first ? sw * (scales[1] * (1.0f / 127.0f)) : facR;

    const char* pxp = (const char*)(xgc + ((size_t)(b0 + gq) * Tc) * 1024 + col * 4);
    ushort4 px0 = *(const ushort4*)pxp;
    ushort4 px1 = *(const ushort4*)(pxp + 128);
    pxp += 2048;

    const bool mrow = (c16 & 3) == 0;  // A-lanes: M-rows 0,4,8,12
    const int  hrow = c16 >> 2;
    i32x4 af[4];
#pragma unroll
    for (int kt = 0; kt < 4; ++kt) { i32x4 z = {0, 0, 0, 0}; af[kt] = z; }
    const i32x4 zacc = {0, 0, 0, 0};
    int q0 = 0, q1 = 0;

    __syncthreads();

    for (int tt = 0; tt < Tc; ++tt) {
      const int cur = tt & 1;

      // A fragments first (feed the first MFMA)
      if (mrow) {
        const signed char* hp = &hb[cur][hrow * 320 + gq * 16];
        af[0] = *(const i32x4*)(hp);
        af[1] = *(const i32x4*)(hp + 64);
        af[2] = *(const i32x4*)(hp + 128);
        af[3] = *(const i32x4*)(hp + 192);
      }

      // prefetch next step's xg (last iter reads into adjacent ws region; unused)
      ushort4 pn0 = *(const ushort4*)pxp;
      ushort4 pn1 = *(const ushort4*)(pxp + 128);
      pxp += 2048;

      i32x4 acc[8];
      // even accs first (outputs for col): their results unblock elementwise-0
#pragma unroll
      for (int ne = 0; ne < 4; ++ne)
        acc[2 * ne] = __builtin_amdgcn_mfma_i32_16x16x64_i8(af[0], wf[2 * ne][0], zacc, 0, 0, 0);
#pragma unroll
      for (int kt = 1; kt < 4; ++kt)
#pragma unroll
        for (int ne = 0; ne < 4; ++ne)
          acc[2 * ne] = __builtin_amdgcn_mfma_i32_16x16x64_i8(af[kt], wf[2 * ne][kt], acc[2 * ne], 0, 0, 0);
      // odd accs (outputs for col+16)
#pragma unroll
      for (int ne = 0; ne < 4; ++ne)
        acc[2 * ne + 1] = __builtin_amdgcn_mfma_i32_16x16x64_i8(af[0], wf[2 * ne + 1][0], zacc, 0, 0, 0);
#pragma unroll
      for (int kt = 1; kt < 4; ++kt)
#pragma unroll
        for (int ne = 0; ne < 4; ++ne)
          acc[2 * ne + 1] = __builtin_amdgcn_mfma_i32_16x16x64_i8(af[kt], wf[2 * ne + 1][kt], acc[2 * ne + 1], 0, 0, 0);

      const float fac = (tt == 0) ? fac0 : facR;

      // D row = gq*4 + reg -> reg 0 of every gq group is a real batch row (gq).
      {
        float gi = __builtin_fmaf((float)acc[0][0], fac, h2f(px0.x));
        float gf = __builtin_fmaf((float)acc[2][0], fac, h2f(px0.y));
        float gg = __builtin_fmaf((float)acc[4][0], fac, h2f(px0.z));
        float go = __builtin_fmaf((float)acc[6][0], fac, h2f(px0.w));
        cv0 = fast_sigmoid(gf) * cv0 + fast_sigmoid(gi) * fast_tanh(gg);
        float hn = fast_sigmoid(go) * fast_tanh(cv0);
        q0 = (int)rintf(hn * 127.0f);
        hb[cur ^ 1][gq * 320 + col] = (signed char)q0;
      }
      {
        float gi = __builtin_fmaf((float)acc[1][0], fac, h2f(px1.x));
        float gf = __builtin_fmaf((float)acc[3][0], fac, h2f(px1.y));
        float gg = __builtin_fmaf((float)acc[5][0], fac, h2f(px1.z));
        float go = __builtin_fmaf((float)acc[7][0], fac, h2f(px1.w));
        cv1 = fast_sigmoid(gf) * cv1 + fast_sigmoid(gi) * fast_tanh(gg);
        float hn = fast_sigmoid(go) * fast_tanh(cv1);
        q1 = (int)rintf(hn * 127.0f);
        hb[cur ^ 1][gq * 320 + col + 16] = (signed char)q1;
      }

      px0 = pn0; px1 = pn1;
      __syncthreads();
    }

    cst[(b0 + gq) * 256 + col]      = cv0;
    cst[(b0 + gq) * 256 + col + 16] = cv1;
    hst[(b0 + gq) * 256 + col]      = (signed char)q0;
    hst[(b0 + gq) * 256 + col + 16] = (signed char)q1;
    if (last) {
      out[(b0 + gq) * 256 + col]      = cv0;
      out[(b0 + gq) * 256 + col + 16] = cv1;
    }
  } else if (do_x) {
    // ------------------------------ XGEMM for chunk c+1 (512 threads/tile)
    unsigned short* Ash = (unsigned short*)smem;            // 128x128 f16
    unsigned short* Bsh = (unsigned short*)(smem + 32768);  // 128x128 f16
    const int tcm    = (1 << tclog) - 1;
    const int ntiles = Tc << 2;          // (512*Tc)/128
    const int wm = wv >> 2, wn = wv & 3; // 2x4 wave grid
    const int mh = wm * 64, nh = wn * 32;

    for (int rt = (int)blockIdx.x - 128; rt < ntiles; rt += 128) {
      const long m0 = (long)rt * 128;
      __syncthreads();  // previous tile's readers done before re-staging

      // stage A: 128 rows x 128 k, f32 -> f16, swizzled
#pragma unroll
      for (int i = 0; i < 8; ++i) {
        int fidx = (i * 512 + tid) * 4;
        int row = fidx >> 7, k = fidx & 127;
        long cr = m0 + row;
        long b  = cr >> tclog;
        long tl = cr & tcm;
        f32x4 v = *(const f32x4*)(x + ((size_t)b * 512 + t0n + tl) * 128 + k);
        ushort4 pk;
        pk.x = f2h(v[0]); pk.y = f2h(v[1]); pk.z = f2h(v[2]); pk.w = f2h(v[3]);
        int byte = (row * 256 + k * 2) ^ ((row & 7) << 4);
        *(ushort4*)((char*)Ash + byte) = pk;
      }

      for (int nc = 0; nc < 8; ++nc) {
        __syncthreads();
        {
          const char* wb = (const char*)(wih + nc * 128 * 128);
#pragma unroll
          for (int i = 0; i < 4; ++i) {
            int idx16 = i * 512 + tid;
            int row = idx16 >> 4, ch = idx16 & 15;
            int srcoff = row * 256 + ((ch * 16) ^ ((row & 7) << 4));
            u32x4 v = *(const u32x4*)(wb + srcoff);
            *(u32x4*)((char*)Bsh + idx16 * 16) = v;
          }
        }
        __syncthreads();

        float bias_v[2];
#pragma unroll
        for (int nt = 0; nt < 2; ++nt)
          bias_v[nt] = bconv[nc * 128 + nh + nt * 16 + c16];

        f16x8 af[4][4], bfr[2][4];
#pragma unroll
        for (int sm = 0; sm < 4; ++sm)
#pragma unroll
          for (int kt = 0; kt < 4; ++kt) {
            int m = mh + sm * 16 + c16;
            int byte = (m * 256 + (kt * 32 + gq * 8) * 2) ^ ((m & 7) << 4);
            af[sm][kt] = __builtin_bit_cast(f16x8, *(const u32x4*)((const char*)Ash + byte));
          }
#pragma unroll
        for (int nt = 0; nt < 2; ++nt)
#pragma unroll
          for (int kt = 0; kt < 4; ++kt) {
            int n = nh + nt * 16 + c16;
            int byte = (n * 256 + (kt * 32 + gq * 8) * 2) ^ ((n & 7) << 4);
            bfr[nt][kt] = __builtin_bit_cast(f16x8, *(const u32x4*)((const char*)Bsh + byte));
          }

        f32x4 acc[4][2];
#pragma unroll
        for (int sm = 0; sm < 4; ++sm)
#pragma unroll
          for (int nt = 0; nt < 2; ++nt) { f32x4 z = {0.f, 0.f, 0.f, 0.f}; acc[sm][nt] = z; }
#pragma unroll
        for (int sm = 0; sm < 4; ++sm)
#pragma unroll
          for (int nt = 0; nt < 2; ++nt)
#pragma unroll
            for (int kt = 0; kt < 4; ++kt)
              acc[sm][nt] = __builtin_amdgcn_mfma_f32_16x16x32_f16(af[sm][kt], bfr[nt][kt], acc[sm][nt], 0, 0, 0);

#pragma unroll
        for (int sm = 0; sm < 4; ++sm)
#pragma unroll
          for (int nt = 0; nt < 2; ++nt) {
            long row = m0 + mh + sm * 16 + gq * 4;
            int gcol = nc * 128 + nh + nt * 16 + c16;
#pragma unroll
            for (int r = 0; r < 4; ++r)
              xgn[(size_t)(row + r) * 1024 + gcol] = f2h(acc[sm][nt][r] + bias_v[nt]);
          }
      }
    }
  }
}

// ---------------------------------------------------------------- launch
extern "C" void kernel_launch(void* const* d_in, const int* in_sizes, int n_in,
                              void* d_out, int out_size, void* d_ws, size_t ws_size,
                              hipStream_t stream) {
  const float* x   = (const float*)d_in[0];
  const float* h0  = (const float*)d_in[1];
  const float* c0  = (const float*)d_in[2];
  const float* wih = (const float*)d_in[3];
  const float* whh = (const float*)d_in[4];
  const float* bih = (const float*)d_in[5];
  const float* bhh = (const float*)d_in[6];
  float* out = (float*)d_out;

  const size_t fixed = 262144u /*wih f16*/ + 262144u /*wq*/ + 131072u /*hst*/
                     + 524288u /*cst*/ + 4096u /*bconv*/ + 256u /*scales*/;
  int tc = 512;
  while (tc > 4 && 2u * (size_t)512 * tc * 2048 + fixed > ws_size) tc >>= 1;
  int tclog = 31 - __builtin_clz((unsigned)tc);
  size_t bufsz = (size_t)512 * tc * 2048;

  char* ws = (char*)d_ws;
  unsigned short* xgb0  = (unsigned short*)ws;
  unsigned short* xgb1  = (unsigned short*)(ws + bufsz);
  size_t off = 2u * bufsz;
  unsigned short* wih_h = (unsigned short*)(ws + off);  off += 262144u;
  signed char*    wqb   = (signed char*)(ws + off);     off += 262144u;
  signed char*    hst   = (signed char*)(ws + off);     off += 131072u;
  float*          cst   = (float*)(ws + off);           off += 524288u;
  float*          bcv   = (float*)(ws + off);           off += 4096u;
  float*          scl   = (float*)(ws + off);

  zero2<<<1, 64, 0, stream>>>(scl);
  absmax_red<<<128, 256, 0, stream>>>(whh, 262144, scl + 0);
  absmax_red<<<64, 256, 0, stream>>>(h0, 131072, scl + 1);
  wperm_cast<<<128, 256, 0, stream>>>(wih, wih_h);
  bias_perm<<<4, 256, 0, stream>>>(bih, bhh, bcv);
  quant_w<<<1024, 256, 0, stream>>>(whh, scl, wqb, 262144);
  state_init<<<512, 256, 0, stream>>>(h0, c0, scl, hst, cst);

  // prologue: xgemm for chunk 0 (full chip)
  xgemm<<<4 * tc, 256, 0, stream>>>(x, wih_h, bcv, xgb0, 0, tclog);

  int NC = 512 / tc;
  for (int c = 0; c < NC; ++c) {
    unsigned short* cur = (c & 1) ? xgb1 : xgb0;
    unsigned short* nxt = (c & 1) ? xgb0 : xgb1;
    int do_x = (c + 1 < NC) ? 1 : 0;
    fused_chunk<<<256, 512, 0, stream>>>(
        cur, wqb, scl, hst, cst, out, tc, (c == 0) ? 1 : 0, (c == NC - 1) ? 1 : 0,
        x, wih_h, bcv, nxt, (c + 1) * tc, tclog, do_x);
  }
}

// Round 8
// 541.756 us; speedup vs baseline: 1.0131x; 1.0131x over previous
//
#include <hip/hip_runtime.h>
#include <hip/hip_bf16.h>
#include <hip/hip_fp16.h>

// LSTM: B=512, T=512, I=128, H=256, gates G=4H=1024 (PyTorch i,f,g,o order).
// Fused pipeline: per chunk c, ONE launch runs lstm(chunk c) on blocks 0-127
// (R=4 batch rows/block, w_hh i8 pinned in 128 VGPRs/thread, M-rows {0,4,8,12})
// concurrently with xgemm(chunk c+1) on blocks 128-255. Kernel boundary = dep.
// Round-8 fix: amdgpu_waves_per_eu(2,2) -> 256-VGPR regalloc budget, plus a
// memory clobber after the wf loads so rematerializing the weight loads inside
// the loop is illegal. (R6/R7: compiler re-fetched 2KB/thread/step from L2 ->
// ~30 TB/s aggregate = L2-bound, MfmaUtil 25%.)

typedef __attribute__((ext_vector_type(4))) float f32x4;
typedef __attribute__((ext_vector_type(8))) _Float16 f16x8;
typedef __attribute__((ext_vector_type(4))) unsigned int u32x4;
typedef __attribute__((ext_vector_type(4))) int i32x4;

static __device__ __forceinline__ float h2f(unsigned short u) {
  return (float)__builtin_bit_cast(_Float16, u);
}
static __device__ __forceinline__ unsigned short f2h(float f) {
  return __builtin_bit_cast(unsigned short, (_Float16)f);
}
static __device__ __forceinline__ float fast_sigmoid(float x) {
  return __builtin_amdgcn_rcpf(1.0f + __builtin_amdgcn_exp2f(-1.44269504f * x));
}
static __device__ __forceinline__ float fast_tanh(float x) {
  return 1.0f - 2.0f * __builtin_amdgcn_rcpf(1.0f + __builtin_amdgcn_exp2f(2.88539008f * x));
}

// ---------------------------------------------------------------- small utils
__global__ void zero2(float* p) { if (threadIdx.x < 2) p[threadIdx.x] = 0.f; }

__global__ void absmax_red(const float* __restrict__ src, int n, float* __restrict__ out) {
  __shared__ float s[256];
  float m = 0.f;
  for (int i = blockIdx.x * 256 + threadIdx.x; i < n; i += gridDim.x * 256)
    m = fmaxf(m, fabsf(src[i]));
  s[threadIdx.x] = m; __syncthreads();
  for (int w = 128; w > 0; w >>= 1) {
    if (threadIdx.x < w) s[threadIdx.x] = fmaxf(s[threadIdx.x], s[threadIdx.x + w]);
    __syncthreads();
  }
  if (threadIdx.x == 0) atomicMax((int*)out, __float_as_int(s[0]));
}

__global__ void quant_w(const float* __restrict__ w, const float* __restrict__ scales,
                        signed char* __restrict__ wq, int n) {
  int i = blockIdx.x * 256 + threadIdx.x;
  if (i < n) {
    float inv = 127.0f / scales[0];
    int q = (int)rintf(w[i] * inv);
    q = max(-127, min(127, q));
    wq[i] = (signed char)q;
  }
}

// w_ih cast with gate-row interleave: dst row q <- src row (q&3)*256 + (q>>2)
__global__ void wperm_cast(const float* __restrict__ w, unsigned short* __restrict__ dst) {
  int i = (blockIdx.x * 256 + threadIdx.x) * 4;  // over 131072
  if (i < 131072) {
    int q = i >> 7, k = i & 127;
    int p = (q & 3) * 256 + (q >> 2);
    f32x4 v = *(const f32x4*)(w + p * 128 + k);
    ushort4 pk;
    pk.x = f2h(v[0]); pk.y = f2h(v[1]); pk.z = f2h(v[2]); pk.w = f2h(v[3]);
    *(ushort4*)(dst + i) = pk;
  }
}

__global__ void bias_perm(const float* __restrict__ bi, const float* __restrict__ bh,
                          float* __restrict__ bc) {
  int q = blockIdx.x * 256 + threadIdx.x;  // 1024
  int p = (q & 3) * 256 + (q >> 2);
  bc[q] = bi[p] + bh[p];
}

__global__ void state_init(const float* __restrict__ h0, const float* __restrict__ c0,
                           const float* __restrict__ scales,
                           signed char* __restrict__ hst, float* __restrict__ cst) {
  int i = blockIdx.x * 256 + threadIdx.x;  // grid 512 -> 131072
  float inv = 127.0f / scales[1];
  int q = (int)rintf(h0[i] * inv);
  q = max(-127, min(127, q));
  hst[i] = (signed char)q;
  cst[i] = c0[i];
}

// ---------------------------------------------------------------- prologue gemm
__global__ __launch_bounds__(256) void xgemm(
    const float* __restrict__ x, const unsigned short* __restrict__ wih,
    const float* __restrict__ bconv,
    unsigned short* __restrict__ xg, int t0, int tclog) {
  __shared__ unsigned short Ash[128 * 128];
  __shared__ unsigned short Bsh[128 * 128];

  const int tid  = threadIdx.x;
  const int lane = tid & 63;
  const int wv   = tid >> 6;
  const int c16  = lane & 15;
  const int gq   = lane >> 4;
  const long m0  = (long)blockIdx.x * 128;
  const int tcm  = (1 << tclog) - 1;

#pragma unroll
  for (int i = 0; i < 16; ++i) {
    int fidx = (i * 256 + tid) * 4;
    int row = fidx >> 7, k = fidx & 127;
    long cr = m0 + row;
    long b  = cr >> tclog;
    long tl = cr & tcm;
    f32x4 v = *(const f32x4*)(x + ((size_t)b * 512 + t0 + tl) * 128 + k);
    ushort4 pk;
    pk.x = f2h(v[0]); pk.y = f2h(v[1]); pk.z = f2h(v[2]); pk.w = f2h(v[3]);
    int byte = (row * 256 + k * 2) ^ ((row & 7) << 4);
    *(ushort4*)((char*)Ash + byte) = pk;
  }

  const int mh = (wv >> 1) * 64;
  const int nh = (wv & 1) * 64;

  for (int nc = 0; nc < 8; ++nc) {
    __syncthreads();
    {
      const char* wb = (const char*)(wih + nc * 128 * 128);
#pragma unroll
      for (int i = 0; i < 8; ++i) {
        int idx16 = i * 256 + tid;
        int row = idx16 >> 4, ch = idx16 & 15;
        int srcoff = row * 256 + ((ch * 16) ^ ((row & 7) << 4));
        u32x4 v = *(const u32x4*)(wb + srcoff);
        *(u32x4*)((char*)Bsh + idx16 * 16) = v;
      }
    }
    __syncthreads();

    float bias_v[4];
#pragma unroll
    for (int nt = 0; nt < 4; ++nt)
      bias_v[nt] = bconv[nc * 128 + nh + nt * 16 + c16];

    f16x8 af[4][4], bfr[4][4];
#pragma unroll
    for (int sm = 0; sm < 4; ++sm)
#pragma unroll
      for (int kt = 0; kt < 4; ++kt) {
        int m = mh + sm * 16 + c16;
        int byte = (m * 256 + (kt * 32 + gq * 8) * 2) ^ ((m & 7) << 4);
        af[sm][kt] = __builtin_bit_cast(f16x8, *(const u32x4*)((const char*)Ash + byte));
      }
#pragma unroll
    for (int nt = 0; nt < 4; ++nt)
#pragma unroll
      for (int kt = 0; kt < 4; ++kt) {
        int n = nh + nt * 16 + c16;
        int byte = (n * 256 + (kt * 32 + gq * 8) * 2) ^ ((n & 7) << 4);
        bfr[nt][kt] = __builtin_bit_cast(f16x8, *(const u32x4*)((const char*)Bsh + byte));
      }

    f32x4 acc[4][4];
#pragma unroll
    for (int sm = 0; sm < 4; ++sm)
#pragma unroll
      for (int nt = 0; nt < 4; ++nt) { f32x4 z = {0.f, 0.f, 0.f, 0.f}; acc[sm][nt] = z; }
#pragma unroll
    for (int sm = 0; sm < 4; ++sm)
#pragma unroll
      for (int nt = 0; nt < 4; ++nt)
#pragma unroll
        for (int kt = 0; kt < 4; ++kt)
          acc[sm][nt] = __builtin_amdgcn_mfma_f32_16x16x32_f16(af[sm][kt], bfr[nt][kt], acc[sm][nt], 0, 0, 0);

#pragma unroll
    for (int sm = 0; sm < 4; ++sm)
#pragma unroll
      for (int nt = 0; nt < 4; ++nt) {
        long row = m0 + mh + sm * 16 + gq * 4;
        int gcol = nc * 128 + nh + nt * 16 + c16;
#pragma unroll
        for (int r = 0; r < 4; ++r)
          xg[(size_t)(row + r) * 1024 + gcol] = f2h(acc[sm][nt][r] + bias_v[nt]);
      }
  }
}

// ---------------------------------------------------------------- fused kernel
// blocks 0-127: lstm chunk c (4 batch rows each). blocks 128-255: xgemm c+1.
// waves_per_eu(2,2): pin regalloc budget to 256 VGPR (1 block/CU; grid=256).
__global__ __launch_bounds__(512)
__attribute__((amdgpu_waves_per_eu(2, 2)))
void fused_chunk(
    const unsigned short* __restrict__ xgc, const signed char* __restrict__ wq,
    const float* __restrict__ scales, signed char* __restrict__ hst,
    float* __restrict__ cst, float* __restrict__ out, int Tc, int first, int last,
    const float* __restrict__ x, const unsigned short* __restrict__ wih,
    const float* __restrict__ bconv, unsigned short* __restrict__ xgn,
    int t0n, int tclog, int do_x) {
  __shared__ char smem[65536];

  const int tid  = threadIdx.x;
  const int lane = tid & 63;
  const int wv   = tid >> 6;      // 0..7
  const int c16  = lane & 15;
  const int gq   = lane >> 4;     // 0..3

  if (blockIdx.x < 128) {
    // ------------------------------ LSTM: 4 batch rows, M-rows {0,4,8,12}
    signed char (*hb)[1280] = (signed char (*)[1280])smem;  // [buf][4 rows x 320B]
    const int b0 = blockIdx.x * 4;

    const int col = wv * 32 + c16;     // output cols: col and col+16; row = gq
    float cv0 = cst[(b0 + gq) * 256 + col];
    float cv1 = cst[(b0 + gq) * 256 + col + 16];

    const float sw   = scales[0] * (1.0f / 127.0f);
    const float facR = sw * (1.0f / 127.0f);
    const float fac0 = first ? sw * (scales[1] * (1.0f / 127.0f)) : facR;

    // weights: n = (nt>>1)*256 + wv*32 + (nt&1)*16 + c16 ; k = kt*64 + gq*16
    i32x4 wf[8][4];
#pragma unroll
    for (int nt = 0; nt < 8; ++nt)
#pragma unroll
      for (int kt = 0; kt < 4; ++kt) {
        int n = (nt >> 1) * 256 + wv * 32 + (nt & 1) * 16 + c16;
        wf[nt][kt] = *(const i32x4*)(wq + n * 256 + kt * 64 + gq * 16);
      }
    // pin in VGPRs, then poison the compiler's memory model so re-loading wq
    // later cannot be proven equivalent -> rematerialization is illegal.
#pragma unroll
    for (int nt = 0; nt < 8; ++nt)
#pragma unroll
      for (int kt = 0; kt < 4; ++kt)
        asm volatile("" : "+v"(wf[nt][kt]));
    asm volatile("" ::: "memory");

    // init hb[0]: rows 0..3 (stride 320B), cols 0..255
    for (int i = tid; i < 1024; i += 512) {
      int row = i >> 8, cc = i & 255;
      hb[0][row * 320 + cc] = hst[(b0 + row) * 256 + cc];
    }

    const char* pxp = (const char*)(xgc + ((size_t)(b0 + gq) * Tc) * 1024 + col * 4);
    ushort4 px0 = *(const ushort4*)pxp;
    ushort4 px1 = *(const ushort4*)(pxp + 128);
    pxp += 2048;

    const bool mrow = (c16 & 3) == 0;  // A-lanes: M-rows 0,4,8,12
    const int  hrow = c16 >> 2;
    i32x4 af[4];
#pragma unroll
    for (int kt = 0; kt < 4; ++kt) { i32x4 z = {0, 0, 0, 0}; af[kt] = z; }
    const i32x4 zacc = {0, 0, 0, 0};
    int q0 = 0, q1 = 0;

    __syncthreads();

    for (int tt = 0; tt < Tc; ++tt) {
      const int cur = tt & 1;

      // A fragments first (feed the first MFMA)
      if (mrow) {
        const signed char* hp = &hb[cur][hrow * 320 + gq * 16];
        af[0] = *(const i32x4*)(hp);
        af[1] = *(const i32x4*)(hp + 64);
        af[2] = *(const i32x4*)(hp + 128);
        af[3] = *(const i32x4*)(hp + 192);
      }

      // prefetch next step's xg (last iter reads into adjacent ws region; unused)
      ushort4 pn0 = *(const ushort4*)pxp;
      ushort4 pn1 = *(const ushort4*)(pxp + 128);
      pxp += 2048;

      i32x4 acc[8];
      // even accs first (outputs for col): their results unblock elementwise-0
#pragma unroll
      for (int ne = 0; ne < 4; ++ne)
        acc[2 * ne] = __builtin_amdgcn_mfma_i32_16x16x64_i8(af[0], wf[2 * ne][0], zacc, 0, 0, 0);
#pragma unroll
      for (int kt = 1; kt < 4; ++kt)
#pragma unroll
        for (int ne = 0; ne < 4; ++ne)
          acc[2 * ne] = __builtin_amdgcn_mfma_i32_16x16x64_i8(af[kt], wf[2 * ne][kt], acc[2 * ne], 0, 0, 0);
      // odd accs (outputs for col+16)
#pragma unroll
      for (int ne = 0; ne < 4; ++ne)
        acc[2 * ne + 1] = __builtin_amdgcn_mfma_i32_16x16x64_i8(af[0], wf[2 * ne + 1][0], zacc, 0, 0, 0);
#pragma unroll
      for (int kt = 1; kt < 4; ++kt)
#pragma unroll
        for (int ne = 0; ne < 4; ++ne)
          acc[2 * ne + 1] = __builtin_amdgcn_mfma_i32_16x16x64_i8(af[kt], wf[2 * ne + 1][kt], acc[2 * ne + 1], 0, 0, 0);

      const float fac = (tt == 0) ? fac0 : facR;

      // D row = gq*4 + reg -> reg 0 of every gq group is a real batch row (gq).
      {
        float gi = __builtin_fmaf((float)acc[0][0], fac, h2f(px0.x));
        float gf = __builtin_fmaf((float)acc[2][0], fac, h2f(px0.y));
        float gg = __builtin_fmaf((float)acc[4][0], fac, h2f(px0.z));
        float go = __builtin_fmaf((float)acc[6][0], fac, h2f(px0.w));
        cv0 = fast_sigmoid(gf) * cv0 + fast_sigmoid(gi) * fast_tanh(gg);
        float hn = fast_sigmoid(go) * fast_tanh(cv0);
        q0 = (int)rintf(hn * 127.0f);
        hb[cur ^ 1][gq * 320 + col] = (signed char)q0;
      }
      {
        float gi = __builtin_fmaf((float)acc[1][0], fac, h2f(px1.x));
        float gf = __builtin_fmaf((float)acc[3][0], fac, h2f(px1.y));
        float gg = __builtin_fmaf((float)acc[5][0], fac, h2f(px1.z));
        float go = __builtin_fmaf((float)acc[7][0], fac, h2f(px1.w));
        cv1 = fast_sigmoid(gf) * cv1 + fast_sigmoid(gi) * fast_tanh(gg);
        float hn = fast_sigmoid(go) * fast_tanh(cv1);
        q1 = (int)rintf(hn * 127.0f);
        hb[cur ^ 1][gq * 320 + col + 16] = (signed char)q1;
      }

      px0 = pn0; px1 = pn1;
      __syncthreads();
    }

    cst[(b0 + gq) * 256 + col]      = cv0;
    cst[(b0 + gq) * 256 + col + 16] = cv1;
    hst[(b0 + gq) * 256 + col]      = (signed char)q0;
    hst[(b0 + gq) * 256 + col + 16] = (signed char)q1;
    if (last) {
      out[(b0 + gq) * 256 + col]      = cv0;
      out[(b0 + gq) * 256 + col + 16] = cv1;
    }
  } else if (do_x) {
    // ------------------------------ XGEMM for chunk c+1 (512 threads/tile)
    unsigned short* Ash = (unsigned short*)smem;            // 128x128 f16
    unsigned short* Bsh = (unsigned short*)(smem + 32768);  // 128x128 f16
    const int tcm    = (1 << tclog) - 1;
    const int ntiles = Tc << 2;          // (512*Tc)/128
    const int wm = wv >> 2, wn = wv & 3; // 2x4 wave grid
    const int mh = wm * 64, nh = wn * 32;

    for (int rt = (int)blockIdx.x - 128; rt < ntiles; rt += 128) {
      const long m0 = (long)rt * 128;
      __syncthreads();  // previous tile's readers done before re-staging

      // stage A: 128 rows x 128 k, f32 -> f16, swizzled
#pragma unroll
      for (int i = 0; i < 8; ++i) {
        int fidx = (i * 512 + tid) * 4;
        int row = fidx >> 7, k = fidx & 127;
        long cr = m0 + row;
        long b  = cr >> tclog;
        long tl = cr & tcm;
        f32x4 v = *(const f32x4*)(x + ((size_t)b * 512 + t0n + tl) * 128 + k);
        ushort4 pk;
        pk.x = f2h(v[0]); pk.y = f2h(v[1]); pk.z = f2h(v[2]); pk.w = f2h(v[3]);
        int byte = (row * 256 + k * 2) ^ ((row & 7) << 4);
        *(ushort4*)((char*)Ash + byte) = pk;
      }

      for (int nc = 0; nc < 8; ++nc) {
        __syncthreads();
        {
          const char* wb = (const char*)(wih + nc * 128 * 128);
#pragma unroll
          for (int i = 0; i < 4; ++i) {
            int idx16 = i * 512 + tid;
            int row = idx16 >> 4, ch = idx16 & 15;
            int srcoff = row * 256 + ((ch * 16) ^ ((row & 7) << 4));
            u32x4 v = *(const u32x4*)(wb + srcoff);
            *(u32x4*)((char*)Bsh + idx16 * 16) = v;
          }
        }
        __syncthreads();

        float bias_v[2];
#pragma unroll
        for (int nt = 0; nt < 2; ++nt)
          bias_v[nt] = bconv[nc * 128 + nh + nt * 16 + c16];

        f16x8 af[4][4], bfr[2][4];
#pragma unroll
        for (int sm = 0; sm < 4; ++sm)
#pragma unroll
          for (int kt = 0; kt < 4; ++kt) {
            int m = mh + sm * 16 + c16;
            int byte = (m * 256 + (kt * 32 + gq * 8) * 2) ^ ((m & 7) << 4);
            af[sm][kt] = __builtin_bit_cast(f16x8, *(const u32x4*)((const char*)Ash + byte));
          }
#pragma unroll
        for (int nt = 0; nt < 2; ++nt)
#pragma unroll
          for (int kt = 0; kt < 4; ++kt) {
            int n = nh + nt * 16 + c16;
            int byte = (n * 256 + (kt * 32 + gq * 8) * 2) ^ ((n & 7) << 4);
            bfr[nt][kt] = __builtin_bit_cast(f16x8, *(const u32x4*)((const char*)Bsh + byte));
          }

        f32x4 acc[4][2];
#pragma unroll
        for (int sm = 0; sm < 4; ++sm)
#pragma unroll
          for (int nt = 0; nt < 2; ++nt) { f32x4 z = {0.f, 0.f, 0.f, 0.f}; acc[sm][nt] = z; }
#pragma unroll
        for (int sm = 0; sm < 4; ++sm)
#pragma unroll
          for (int nt = 0; nt < 2; ++nt)
#pragma unroll
            for (int kt = 0; kt < 4; ++kt)
              acc[sm][nt] = __builtin_amdgcn_mfma_f32_16x16x32_f16(af[sm][kt], bfr[nt][kt], acc[sm][nt], 0, 0, 0);

#pragma unroll
        for (int sm = 0; sm < 4; ++sm)
#pragma unroll
          for (int nt = 0; nt < 2; ++nt) {
            long row = m0 + mh + sm * 16 + gq * 4;
            int gcol = nc * 128 + nh + nt * 16 + c16;
#pragma unroll
            for (int r = 0; r < 4; ++r)
              xgn[(size_t)(row + r) * 1024 + gcol] = f2h(acc[sm][nt][r] + bias_v[nt]);
          }
      }
    }
  }
}

// ---------------------------------------------------------------- launch
extern "C" void kernel_launch(void* const* d_in, const int* in_sizes, int n_in,
                              void* d_out, int out_size, void* d_ws, size_t ws_size,
                              hipStream_t stream) {
  const float* x   = (const float*)d_in[0];
  const float* h0  = (const float*)d_in[1];
  const float* c0  = (const float*)d_in[2];
  const float* wih = (const float*)d_in[3];
  const float* whh = (const float*)d_in[4];
  const float* bih = (const float*)d_in[5];
  const float* bhh = (const float*)d_in[6];
  float* out = (float*)d_out;

  const size_t fixed = 262144u /*wih f16*/ + 262144u /*wq*/ + 131072u /*hst*/
                     + 524288u /*cst*/ + 4096u /*bconv*/ + 256u /*scales*/;
  int tc = 512;
  while (tc > 4 && 2u * (size_t)512 * tc * 2048 + fixed > ws_size) tc >>= 1;
  int tclog = 31 - __builtin_clz((unsigned)tc);
  size_t bufsz = (size_t)512 * tc * 2048;

  char* ws = (char*)d_ws;
  unsigned short* xgb0  = (unsigned short*)ws;
  unsigned short* xgb1  = (unsigned short*)(ws + bufsz);
  size_t off = 2u * bufsz;
  unsigned short* wih_h = (unsigned short*)(ws + off);  off += 262144u;
  signed char*    wqb   = (signed char*)(ws + off);     off += 262144u;
  signed char*    hst   = (signed char*)(ws + off);     off += 131072u;
  float*          cst   = (float*)(ws + off);           off += 524288u;
  float*          bcv   = (float*)(ws + off);           off += 4096u;
  float*          scl   = (float*)(ws + off);

  zero2<<<1, 64, 0, stream>>>(scl);
  absmax_red<<<128, 256, 0, stream>>>(whh, 262144, scl + 0);
  absmax_red<<<64, 256, 0, stream>>>(h0, 131072, scl + 1);
  wperm_cast<<<128, 256, 0, stream>>>(wih, wih_h);
  bias_perm<<<4, 256, 0, stream>>>(bih, bhh, bcv);
  quant_w<<<1024, 256, 0, stream>>>(whh, scl, wqb, 262144);
  state_init<<<512, 256, 0, stream>>>(h0, c0, scl, hst, cst);

  // prologue: xgemm for chunk 0 (full chip)
  xgemm<<<4 * tc, 256, 0, stream>>>(x, wih_h, bcv, xgb0, 0, tclog);

  int NC = 512 / tc;
  for (int c = 0; c < NC; ++c) {
    unsigned short* cur = (c & 1) ? xgb1 : xgb0;
    unsigned short* nxt = (c & 1) ? xgb0 : xgb1;
    int do_x = (c + 1 < NC) ? 1 : 0;
    fused_chunk<<<256, 512, 0, stream>>>(
        cur, wqb, scl, hst, cst, out, tc, (c == 0) ? 1 : 0, (c == NC - 1) ? 1 : 0,
        x, wih_h, bcv, nxt, (c + 1) * tc, tclog, do_x);
  }
}

// Round 9
// 531.344 us; speedup vs baseline: 1.0330x; 1.0196x over previous
//
#include <hip/hip_runtime.h>
#include <hip/hip_bf16.h>
#include <hip/hip_fp16.h>

// LSTM: B=512, T=512, I=128, H=256, gates G=4H=1024 (PyTorch i,f,g,o order).
// lstm is AT the i8-MFMA issue wall (1275 cyc/step vs 1306 wall) -> floor
// ~272us. Round 9: minimize everything else: tc=128 (4 chunks; exposed
// prologue xgemm halves; fused = max(68us lstm, ~38us xgemm@half-chip)),
// and 7 prologue kernels merged into 2 (atomic-free absmax via partials).

typedef __attribute__((ext_vector_type(4))) float f32x4;
typedef __attribute__((ext_vector_type(8))) _Float16 f16x8;
typedef __attribute__((ext_vector_type(4))) unsigned int u32x4;
typedef __attribute__((ext_vector_type(4))) int i32x4;

static __device__ __forceinline__ float h2f(unsigned short u) {
  return (float)__builtin_bit_cast(_Float16, u);
}
static __device__ __forceinline__ unsigned short f2h(float f) {
  return __builtin_bit_cast(unsigned short, (_Float16)f);
}
static __device__ __forceinline__ float fast_sigmoid(float x) {
  return __builtin_amdgcn_rcpf(1.0f + __builtin_amdgcn_exp2f(-1.44269504f * x));
}
static __device__ __forceinline__ float fast_tanh(float x) {
  return 1.0f - 2.0f * __builtin_amdgcn_rcpf(1.0f + __builtin_amdgcn_exp2f(2.88539008f * x));
}

// ---------------------------------------------------------------- prep kernels
// scl layout (floats): [0]=sw final, [1]=sh final, [8..135] whh partials,
// [136..199] h0 partials.
__global__ __launch_bounds__(256) void prep1(
    const float* __restrict__ whh, const float* __restrict__ h0,
    const float* __restrict__ wih, const float* __restrict__ bih,
    const float* __restrict__ bhh,
    float* __restrict__ scl, unsigned short* __restrict__ wih_h,
    float* __restrict__ bcv) {
  const int b = blockIdx.x, tid = threadIdx.x;
  if (b < 192) {
    __shared__ float s[256];
    const float* src = (b < 128) ? whh : h0;
    int base = (b < 128) ? b * 2048 : (b - 128) * 2048;
    float m = 0.f;
#pragma unroll
    for (int i = 0; i < 8; ++i) m = fmaxf(m, fabsf(src[base + i * 256 + tid]));
    s[tid] = m; __syncthreads();
    for (int w = 128; w > 0; w >>= 1) {
      if (tid < w) s[tid] = fmaxf(s[tid], s[tid + w]);
      __syncthreads();
    }
    if (tid == 0) scl[8 + b] = s[0];
  } else {
    // w_ih cast + gate-row interleave: dst row q <- src row (q&3)*256 + (q>>2)
    int i = ((b - 192) * 256 + tid) * 4;  // over 131072
    int q = i >> 7, k = i & 127;
    int p = (q & 3) * 256 + (q >> 2);
    f32x4 v = *(const f32x4*)(wih + p * 128 + k);
    ushort4 pk;
    pk.x = f2h(v[0]); pk.y = f2h(v[1]); pk.z = f2h(v[2]); pk.w = f2h(v[3]);
    *(ushort4*)(wih_h + i) = pk;
    if (b == 192) {
      for (int q2 = tid; q2 < 1024; q2 += 256) {
        int p2 = (q2 & 3) * 256 + (q2 >> 2);
        bcv[q2] = bih[p2] + bhh[p2];
      }
    }
  }
}

__global__ __launch_bounds__(256) void prep2(
    const float* __restrict__ whh, const float* __restrict__ h0,
    const float* __restrict__ c0, float* __restrict__ scl,
    signed char* __restrict__ wq, signed char* __restrict__ hst,
    float* __restrict__ cst) {
  __shared__ float s[256];
  const int b = blockIdx.x, tid = threadIdx.x;
  // every block re-reduces the partials locally (no cross-block ordering dep)
  float v = (tid < 128) ? scl[8 + tid] : 0.f;
  s[tid] = v; __syncthreads();
  for (int w = 128; w > 0; w >>= 1) {
    if (tid < w) s[tid] = fmaxf(s[tid], s[tid + w]);
    __syncthreads();
  }
  float sw = s[0]; __syncthreads();
  v = (tid < 64) ? scl[136 + tid] : 0.f;
  s[tid] = v; __syncthreads();
  for (int w = 128; w > 0; w >>= 1) {
    if (tid < w) s[tid] = fmaxf(s[tid], s[tid + w]);
    __syncthreads();
  }
  float sh = s[0];
  if (b == 0 && tid == 0) { scl[0] = sw; scl[1] = sh; }

  // quantize w_hh: 1024 elems/block
  const float invw = 127.0f / sw;
  int base = b * 1024;
#pragma unroll
  for (int i = 0; i < 4; ++i) {
    int idx = base + i * 256 + tid;
    int q = (int)rintf(whh[idx] * invw);
    wq[idx] = (signed char)max(-127, min(127, q));
  }
  // state init: 512 elems/block
  const float invh = 127.0f / sh;
  int sb = b * 512;
#pragma unroll
  for (int i = 0; i < 2; ++i) {
    int idx = sb + i * 256 + tid;
    int q = (int)rintf(h0[idx] * invh);
    hst[idx] = (signed char)max(-127, min(127, q));
    cst[idx] = c0[idx];
  }
}

// ---------------------------------------------------------------- prologue gemm
__global__ __launch_bounds__(256) void xgemm(
    const float* __restrict__ x, const unsigned short* __restrict__ wih,
    const float* __restrict__ bconv,
    unsigned short* __restrict__ xg, int t0, int tclog) {
  __shared__ unsigned short Ash[128 * 128];
  __shared__ unsigned short Bsh[128 * 128];

  const int tid  = threadIdx.x;
  const int lane = tid & 63;
  const int wv   = tid >> 6;
  const int c16  = lane & 15;
  const int gq   = lane >> 4;
  const long m0  = (long)blockIdx.x * 128;
  const int tcm  = (1 << tclog) - 1;

#pragma unroll
  for (int i = 0; i < 16; ++i) {
    int fidx = (i * 256 + tid) * 4;
    int row = fidx >> 7, k = fidx & 127;
    long cr = m0 + row;
    long b  = cr >> tclog;
    long tl = cr & tcm;
    f32x4 v = *(const f32x4*)(x + ((size_t)b * 512 + t0 + tl) * 128 + k);
    ushort4 pk;
    pk.x = f2h(v[0]); pk.y = f2h(v[1]); pk.z = f2h(v[2]); pk.w = f2h(v[3]);
    int byte = (row * 256 + k * 2) ^ ((row & 7) << 4);
    *(ushort4*)((char*)Ash + byte) = pk;
  }

  const int mh = (wv >> 1) * 64;
  const int nh = (wv & 1) * 64;

  for (int nc = 0; nc < 8; ++nc) {
    __syncthreads();
    {
      const char* wb = (const char*)(wih + nc * 128 * 128);
#pragma unroll
      for (int i = 0; i < 8; ++i) {
        int idx16 = i * 256 + tid;
        int row = idx16 >> 4, ch = idx16 & 15;
        int srcoff = row * 256 + ((ch * 16) ^ ((row & 7) << 4));
        u32x4 v = *(const u32x4*)(wb + srcoff);
        *(u32x4*)((char*)Bsh + idx16 * 16) = v;
      }
    }
    __syncthreads();

    float bias_v[4];
#pragma unroll
    for (int nt = 0; nt < 4; ++nt)
      bias_v[nt] = bconv[nc * 128 + nh + nt * 16 + c16];

    f16x8 af[4][4], bfr[4][4];
#pragma unroll
    for (int sm = 0; sm < 4; ++sm)
#pragma unroll
      for (int kt = 0; kt < 4; ++kt) {
        int m = mh + sm * 16 + c16;
        int byte = (m * 256 + (kt * 32 + gq * 8) * 2) ^ ((m & 7) << 4);
        af[sm][kt] = __builtin_bit_cast(f16x8, *(const u32x4*)((const char*)Ash + byte));
      }
#pragma unroll
    for (int nt = 0; nt < 4; ++nt)
#pragma unroll
      for (int kt = 0; kt < 4; ++kt) {
        int n = nh + nt * 16 + c16;
        int byte = (n * 256 + (kt * 32 + gq * 8) * 2) ^ ((n & 7) << 4);
        bfr[nt][kt] = __builtin_bit_cast(f16x8, *(const u32x4*)((const char*)Bsh + byte));
      }

    f32x4 acc[4][4];
#pragma unroll
    for (int sm = 0; sm < 4; ++sm)
#pragma unroll
      for (int nt = 0; nt < 4; ++nt) { f32x4 z = {0.f, 0.f, 0.f, 0.f}; acc[sm][nt] = z; }
#pragma unroll
    for (int sm = 0; sm < 4; ++sm)
#pragma unroll
      for (int nt = 0; nt < 4; ++nt)
#pragma unroll
        for (int kt = 0; kt < 4; ++kt)
          acc[sm][nt] = __builtin_amdgcn_mfma_f32_16x16x32_f16(af[sm][kt], bfr[nt][kt], acc[sm][nt], 0, 0, 0);

#pragma unroll
    for (int sm = 0; sm < 4; ++sm)
#pragma unroll
      for (int nt = 0; nt < 4; ++nt) {
        long row = m0 + mh + sm * 16 + gq * 4;
        int gcol = nc * 128 + nh + nt * 16 + c16;
#pragma unroll
        for (int r = 0; r < 4; ++r)
          xg[(size_t)(row + r) * 1024 + gcol] = f2h(acc[sm][nt][r] + bias_v[nt]);
      }
  }
}

// ---------------------------------------------------------------- fused kernel
// blocks 0-127: lstm chunk c (4 batch rows each). blocks 128-255: xgemm c+1.
__global__ __launch_bounds__(512)
__attribute__((amdgpu_waves_per_eu(2, 2)))
void fused_chunk(
    const unsigned short* __restrict__ xgc, const signed char* __restrict__ wq,
    const float* __restrict__ scales, signed char* __restrict__ hst,
    float* __restrict__ cst, float* __restrict__ out, int Tc, int first, int last,
    const float* __restrict__ x, const unsigned short* __restrict__ wih,
    const float* __restrict__ bconv, unsigned short* __restrict__ xgn,
    int t0n, int tclog, int do_x) {
  __shared__ char smem[65536];

  const int tid  = threadIdx.x;
  const int lane = tid & 63;
  const int wv   = tid >> 6;      // 0..7
  const int c16  = lane & 15;
  const int gq   = lane >> 4;     // 0..3

  if (blockIdx.x < 128) {
    // ------------------------------ LSTM: 4 batch rows, M-rows {0,4,8,12}
    signed char (*hb)[1280] = (signed char (*)[1280])smem;  // [buf][4 rows x 320B]
    const int b0 = blockIdx.x * 4;

    const int col = wv * 32 + c16;     // output cols: col and col+16; row = gq
    float cv0 = cst[(b0 + gq) * 256 + col];
    float cv1 = cst[(b0 + gq) * 256 + col + 16];

    const float sw   = scales[0] * (1.0f / 127.0f);
    const float facR = sw * (1.0f / 127.0f);
    const float fac0 = first ? sw * (scales[1] * (1.0f / 127.0f)) : facR;

    // weights: n = (nt>>1)*256 + wv*32 + (nt&1)*16 + c16 ; k = kt*64 + gq*16
    i32x4 wf[8][4];
#pragma unroll
    for (int nt = 0; nt < 8; ++nt)
#pragma unroll
      for (int kt = 0; kt < 4; ++kt) {
        int n = (nt >> 1) * 256 + wv * 32 + (nt & 1) * 16 + c16;
        wf[nt][kt] = *(const i32x4*)(wq + n * 256 + kt * 64 + gq * 16);
      }
#pragma unroll
    for (int nt = 0; nt < 8; ++nt)
#pragma unroll
      for (int kt = 0; kt < 4; ++kt)
        asm volatile("" : "+v"(wf[nt][kt]));
    asm volatile("" ::: "memory");

    // init hb[0]: rows 0..3 (stride 320B), cols 0..255
    for (int i = tid; i < 1024; i += 512) {
      int row = i >> 8, cc = i & 255;
      hb[0][row * 320 + cc] = hst[(b0 + row) * 256 + cc];
    }

    const char* pxp = (const char*)(xgc + ((size_t)(b0 + gq) * Tc) * 1024 + col * 4);
    ushort4 px0 = *(const ushort4*)pxp;
    ushort4 px1 = *(const ushort4*)(pxp + 128);
    pxp += 2048;

    const bool mrow = (c16 & 3) == 0;  // A-lanes: M-rows 0,4,8,12
    const int  hrow = c16 >> 2;
    i32x4 af[4];
#pragma unroll
    for (int kt = 0; kt < 4; ++kt) { i32x4 z = {0, 0, 0, 0}; af[kt] = z; }
    const i32x4 zacc = {0, 0, 0, 0};
    int q0 = 0, q1 = 0;

    __syncthreads();

    for (int tt = 0; tt < Tc; ++tt) {
      const int cur = tt & 1;

      if (mrow) {
        const signed char* hp = &hb[cur][hrow * 320 + gq * 16];
        af[0] = *(const i32x4*)(hp);
        af[1] = *(const i32x4*)(hp + 64);
        af[2] = *(const i32x4*)(hp + 128);
        af[3] = *(const i32x4*)(hp + 192);
      }

      // prefetch next step's xg (last iter reads into adjacent ws region; unused)
      ushort4 pn0 = *(const ushort4*)pxp;
      ushort4 pn1 = *(const ushort4*)(pxp + 128);
      pxp += 2048;

      i32x4 acc[8];
#pragma unroll
      for (int ne = 0; ne < 4; ++ne)
        acc[2 * ne] = __builtin_amdgcn_mfma_i32_16x16x64_i8(af[0], wf[2 * ne][0], zacc, 0, 0, 0);
#pragma unroll
      for (int kt = 1; kt < 4; ++kt)
#pragma unroll
        for (int ne = 0; ne < 4; ++ne)
          acc[2 * ne] = __builtin_amdgcn_mfma_i32_16x16x64_i8(af[kt], wf[2 * ne][kt], acc[2 * ne], 0, 0, 0);
#pragma unroll
      for (int ne = 0; ne < 4; ++ne)
        acc[2 * ne + 1] = __builtin_amdgcn_mfma_i32_16x16x64_i8(af[0], wf[2 * ne + 1][0], zacc, 0, 0, 0);
#pragma unroll
      for (int kt = 1; kt < 4; ++kt)
#pragma unroll
        for (int ne = 0; ne < 4; ++ne)
          acc[2 * ne + 1] = __builtin_amdgcn_mfma_i32_16x16x64_i8(af[kt], wf[2 * ne + 1][kt], acc[2 * ne + 1], 0, 0, 0);

      const float fac = (tt == 0) ? fac0 : facR;

      {
        float gi = __builtin_fmaf((float)acc[0][0], fac, h2f(px0.x));
        float gf = __builtin_fmaf((float)acc[2][0], fac, h2f(px0.y));
        float gg = __builtin_fmaf((float)acc[4][0], fac, h2f(px0.z));
        float go = __builtin_fmaf((float)acc[6][0], fac, h2f(px0.w));
        cv0 = fast_sigmoid(gf) * cv0 + fast_sigmoid(gi) * fast_tanh(gg);
        float hn = fast_sigmoid(go) * fast_tanh(cv0);
        q0 = (int)rintf(hn * 127.0f);
        hb[cur ^ 1][gq * 320 + col] = (signed char)q0;
      }
      {
        float gi = __builtin_fmaf((float)acc[1][0], fac, h2f(px1.x));
        float gf = __builtin_fmaf((float)acc[3][0], fac, h2f(px1.y));
        float gg = __builtin_fmaf((float)acc[5][0], fac, h2f(px1.z));
        float go = __builtin_fmaf((float)acc[7][0], fac, h2f(px1.w));
        cv1 = fast_sigmoid(gf) * cv1 + fast_sigmoid(gi) * fast_tanh(gg);
        float hn = fast_sigmoid(go) * fast_tanh(cv1);
        q1 = (int)rintf(hn * 127.0f);
        hb[cur ^ 1][gq * 320 + col + 16] = (signed char)q1;
      }

      px0 = pn0; px1 = pn1;
      __syncthreads();
    }

    cst[(b0 + gq) * 256 + col]      = cv0;
    cst[(b0 + gq) * 256 + col + 16] = cv1;
    hst[(b0 + gq) * 256 + col]      = (signed char)q0;
    hst[(b0 + gq) * 256 + col + 16] = (signed char)q1;
    if (last) {
      out[(b0 + gq) * 256 + col]      = cv0;
      out[(b0 + gq) * 256 + col + 16] = cv1;
    }
  } else if (do_x) {
    // ------------------------------ XGEMM for chunk c+1 (512 threads/tile)
    unsigned short* Ash = (unsigned short*)smem;            // 128x128 f16
    unsigned short* Bsh = (unsigned short*)(smem + 32768);  // 128x128 f16
    const int tcm    = (1 << tclog) - 1;
    const int ntiles = Tc << 2;          // (512*Tc)/128
    const int wm = wv >> 2, wn = wv & 3; // 2x4 wave grid
    const int mh = wm * 64, nh = wn * 32;

    for (int rt = (int)blockIdx.x - 128; rt < ntiles; rt += 128) {
      const long m0 = (long)rt * 128;
      __syncthreads();  // previous tile's readers done before re-staging

#pragma unroll
      for (int i = 0; i < 8; ++i) {
        int fidx = (i * 512 + tid) * 4;
        int row = fidx >> 7, k = fidx & 127;
        long cr = m0 + row;
        long b  = cr >> tclog;
        long tl = cr & tcm;
        f32x4 v = *(const f32x4*)(x + ((size_t)b * 512 + t0n + tl) * 128 + k);
        ushort4 pk;
        pk.x = f2h(v[0]); pk.y = f2h(v[1]); pk.z = f2h(v[2]); pk.w = f2h(v[3]);
        int byte = (row * 256 + k * 2) ^ ((row & 7) << 4);
        *(ushort4*)((char*)Ash + byte) = pk;
      }

      for (int nc = 0; nc < 8; ++nc) {
        __syncthreads();
        {
          const char* wb = (const char*)(wih + nc * 128 * 128);
#pragma unroll
          for (int i = 0; i < 4; ++i) {
            int idx16 = i * 512 + tid;
            int row = idx16 >> 4, ch = idx16 & 15;
            int srcoff = row * 256 + ((ch * 16) ^ ((row & 7) << 4));
            u32x4 v = *(const u32x4*)(wb + srcoff);
            *(u32x4*)((char*)Bsh + idx16 * 16) = v;
          }
        }
        __syncthreads();

        float bias_v[2];
#pragma unroll
        for (int nt = 0; nt < 2; ++nt)
          bias_v[nt] = bconv[nc * 128 + nh + nt * 16 + c16];

        f16x8 af[4][4], bfr[2][4];
#pragma unroll
        for (int sm = 0; sm < 4; ++sm)
#pragma unroll
          for (int kt = 0; kt < 4; ++kt) {
            int m = mh + sm * 16 + c16;
            int byte = (m * 256 + (kt * 32 + gq * 8) * 2) ^ ((m & 7) << 4);
            af[sm][kt] = __builtin_bit_cast(f16x8, *(const u32x4*)((const char*)Ash + byte));
          }
#pragma unroll
        for (int nt = 0; nt < 2; ++nt)
#pragma unroll
          for (int kt = 0; kt < 4; ++kt) {
            int n = nh + nt * 16 + c16;
            int byte = (n * 256 + (kt * 32 + gq * 8) * 2) ^ ((n & 7) << 4);
            bfr[nt][kt] = __builtin_bit_cast(f16x8, *(const u32x4*)((const char*)Bsh + byte));
          }

        f32x4 acc[4][2];
#pragma unroll
        for (int sm = 0; sm < 4; ++sm)
#pragma unroll
          for (int nt = 0; nt < 2; ++nt) { f32x4 z = {0.f, 0.f, 0.f, 0.f}; acc[sm][nt] = z; }
#pragma unroll
        for (int sm = 0; sm < 4; ++sm)
#pragma unroll
          for (int nt = 0; nt < 2; ++nt)
#pragma unroll
            for (int kt = 0; kt < 4; ++kt)
              acc[sm][nt] = __builtin_amdgcn_mfma_f32_16x16x32_f16(af[sm][kt], bfr[nt][kt], acc[sm][nt], 0, 0, 0);

#pragma unroll
        for (int sm = 0; sm < 4; ++sm)
#pragma unroll
          for (int nt = 0; nt < 2; ++nt) {
            long row = m0 + mh + sm * 16 + gq * 4;
            int gcol = nc * 128 + nh + nt * 16 + c16;
#pragma unroll
            for (int r = 0; r < 4; ++r)
              xgn[(size_t)(row + r) * 1024 + gcol] = f2h(acc[sm][nt][r] + bias_v[nt]);
          }
      }
    }
  }
}

// ---------------------------------------------------------------- launch
extern "C" void kernel_launch(void* const* d_in, const int* in_sizes, int n_in,
                              void* d_out, int out_size, void* d_ws, size_t ws_size,
                              hipStream_t stream) {
  const float* x   = (const float*)d_in[0];
  const float* h0  = (const float*)d_in[1];
  const float* c0  = (const float*)d_in[2];
  const float* wih = (const float*)d_in[3];
  const float* whh = (const float*)d_in[4];
  const float* bih = (const float*)d_in[5];
  const float* bhh = (const float*)d_in[6];
  float* out = (float*)d_out;

  const size_t fixed = 262144u /*wih f16*/ + 262144u /*wq*/ + 131072u /*hst*/
                     + 524288u /*cst*/ + 4096u /*bconv*/ + 1024u /*scales+parts*/;
  int tc = 128;  // 128 beats 256: halves exposed prologue xgemm; fused stays lstm-bound
  while (tc > 4 && 2u * (size_t)512 * tc * 2048 + fixed > ws_size) tc >>= 1;
  int tclog = 31 - __builtin_clz((unsigned)tc);
  size_t bufsz = (size_t)512 * tc * 2048;

  char* ws = (char*)d_ws;
  unsigned short* xgb0  = (unsigned short*)ws;
  unsigned short* xgb1  = (unsigned short*)(ws + bufsz);
  size_t off = 2u * bufsz;
  unsigned short* wih_h = (unsigned short*)(ws + off);  off += 262144u;
  signed char*    wqb   = (signed char*)(ws + off);     off += 262144u;
  signed char*    hst   = (signed char*)(ws + off);     off += 131072u;
  float*          cst   = (float*)(ws + off);           off += 524288u;
  float*          bcv   = (float*)(ws + off);           off += 4096u;
  float*          scl   = (float*)(ws + off);

  prep1<<<320, 256, 0, stream>>>(whh, h0, wih, bih, bhh, scl, wih_h, bcv);
  prep2<<<256, 256, 0, stream>>>(whh, h0, c0, scl, wqb, hst, cst);

  // prologue: xgemm for chunk 0 (full chip)
  xgemm<<<4 * tc, 256, 0, stream>>>(x, wih_h, bcv, xgb0, 0, tclog);

  int NC = 512 / tc;
  for (int c = 0; c < NC; ++c) {
    unsigned short* cur = (c & 1) ? xgb1 : xgb0;
    unsigned short* nxt = (c & 1) ? xgb0 : xgb1;
    int do_x = (c + 1 < NC) ? 1 : 0;
    fused_chunk<<<256, 512, 0, stream>>>(
        cur, wqb, scl, hst, cst, out, tc, (c == 0) ? 1 : 0, (c == NC - 1) ? 1 : 0,
        x, wih_h, bcv, nxt, (c + 1) * tc, tclog, do_x);
  }
}

// Round 10
// 526.188 us; speedup vs baseline: 1.0431x; 1.0098x over previous
//
#include <hip/hip_runtime.h>
#include <hip/hip_bf16.h>
#include <hip/hip_fp16.h>

// LSTM: B=512, T=512, I=128, H=256, gates G=4H=1024 (PyTorch i,f,g,o order).
// Fused pipeline: blocks 0-127 lstm(chunk c) R=4; blocks 128-255 xgemm(c+1).
// Round-10: adjacent-col lane mapping (w_hh cols permuted at quant time so a
// lane's two outputs are cols 2*c16, 2*c16+1): h-write = 1 ushort/lane, xg
// load = 1 dwordx4/lane, h row stride 288B (banks fully spread). Bit-exact
// relayout; targets the 192 conflict-cycles/block/step + addressing overhead
// in the ~1240-cyc non-MFMA tail (MFMA issue wall is 1306 cyc/step).

typedef __attribute__((ext_vector_type(4))) float f32x4;
typedef __attribute__((ext_vector_type(8))) _Float16 f16x8;
typedef __attribute__((ext_vector_type(4))) unsigned int u32x4;
typedef __attribute__((ext_vector_type(4))) int i32x4;

static __device__ __forceinline__ float h2f(unsigned short u) {
  return (float)__builtin_bit_cast(_Float16, u);
}
static __device__ __forceinline__ unsigned short f2h(float f) {
  return __builtin_bit_cast(unsigned short, (_Float16)f);
}
static __device__ __forceinline__ float fast_sigmoid(float x) {
  return __builtin_amdgcn_rcpf(1.0f + __builtin_amdgcn_exp2f(-1.44269504f * x));
}
static __device__ __forceinline__ float fast_tanh(float x) {
  return 1.0f - 2.0f * __builtin_amdgcn_rcpf(1.0f + __builtin_amdgcn_exp2f(2.88539008f * x));
}

// ---------------------------------------------------------------- prep kernels
// scl layout (floats): [0]=sw, [1]=sh, [8..135] whh partials, [136..199] h0.
__global__ __launch_bounds__(256) void prep1(
    const float* __restrict__ whh, const float* __restrict__ h0,
    const float* __restrict__ wih, const float* __restrict__ bih,
    const float* __restrict__ bhh,
    float* __restrict__ scl, unsigned short* __restrict__ wih_h,
    float* __restrict__ bcv) {
  const int b = blockIdx.x, tid = threadIdx.x;
  if (b < 192) {
    __shared__ float s[256];
    const float* src = (b < 128) ? whh : h0;
    int base = (b < 128) ? b * 2048 : (b - 128) * 2048;
    float m = 0.f;
#pragma unroll
    for (int i = 0; i < 8; ++i) m = fmaxf(m, fabsf(src[base + i * 256 + tid]));
    s[tid] = m; __syncthreads();
    for (int w = 128; w > 0; w >>= 1) {
      if (tid < w) s[tid] = fmaxf(s[tid], s[tid + w]);
      __syncthreads();
    }
    if (tid == 0) scl[8 + b] = s[0];
  } else {
    // w_ih cast + gate-row interleave: dst row q <- src row (q&3)*256 + (q>>2)
    int i = ((b - 192) * 256 + tid) * 4;  // over 131072
    int q = i >> 7, k = i & 127;
    int p = (q & 3) * 256 + (q >> 2);
    f32x4 v = *(const f32x4*)(wih + p * 128 + k);
    ushort4 pk;
    pk.x = f2h(v[0]); pk.y = f2h(v[1]); pk.z = f2h(v[2]); pk.w = f2h(v[3]);
    *(ushort4*)(wih_h + i) = pk;
    if (b == 192) {
      for (int q2 = tid; q2 < 1024; q2 += 256) {
        int p2 = (q2 & 3) * 256 + (q2 >> 2);
        bcv[q2] = bih[p2] + bhh[p2];
      }
    }
  }
}

__global__ __launch_bounds__(256) void prep2(
    const float* __restrict__ whh, const float* __restrict__ h0,
    const float* __restrict__ c0, float* __restrict__ scl,
    signed char* __restrict__ wq, signed char* __restrict__ hst,
    float* __restrict__ cst) {
  __shared__ float s[256];
  const int b = blockIdx.x, tid = threadIdx.x;
  float v = (tid < 128) ? scl[8 + tid] : 0.f;
  s[tid] = v; __syncthreads();
  for (int w = 128; w > 0; w >>= 1) {
    if (tid < w) s[tid] = fmaxf(s[tid], s[tid + w]);
    __syncthreads();
  }
  float sw = s[0]; __syncthreads();
  v = (tid < 64) ? scl[136 + tid] : 0.f;
  s[tid] = v; __syncthreads();
  for (int w = 128; w > 0; w >>= 1) {
    if (tid < w) s[tid] = fmaxf(s[tid], s[tid + w]);
    __syncthreads();
  }
  float sh = s[0];
  if (b == 0 && tid == 0) { scl[0] = sw; scl[1] = sh; }

  // quantize w_hh with adjacent-col permutation: dst row n' holds source
  // column (g*256 + wv*32 + 2*c16 + ntc), where n' = g*256+wv*32+ntc*16+c16.
  const float invw = 127.0f / sw;
  int base = b * 1024;
#pragma unroll
  for (int i = 0; i < 4; ++i) {
    int idx = base + i * 256 + tid;
    int nr = idx >> 8, k = idx & 255;
    int g = nr >> 8, r = nr & 255;
    int wvv = r >> 5, ntc = (r >> 4) & 1, cc = r & 15;
    int src = g * 256 + wvv * 32 + 2 * cc + ntc;
    int q = (int)rintf(whh[src * 256 + k] * invw);
    wq[idx] = (signed char)max(-127, min(127, q));
  }
  // state init: plain col order
  const float invh = 127.0f / sh;
  int sb = b * 512;
#pragma unroll
  for (int i = 0; i < 2; ++i) {
    int idx = sb + i * 256 + tid;
    int q = (int)rintf(h0[idx] * invh);
    hst[idx] = (signed char)max(-127, min(127, q));
    cst[idx] = c0[idx];
  }
}

// ---------------------------------------------------------------- prologue gemm
__global__ __launch_bounds__(256) void xgemm(
    const float* __restrict__ x, const unsigned short* __restrict__ wih,
    const float* __restrict__ bconv,
    unsigned short* __restrict__ xg, int t0, int tclog) {
  __shared__ unsigned short Ash[128 * 128];
  __shared__ unsigned short Bsh[128 * 128];

  const int tid  = threadIdx.x;
  const int lane = tid & 63;
  const int wv   = tid >> 6;
  const int c16  = lane & 15;
  const int gq   = lane >> 4;
  const long m0  = (long)blockIdx.x * 128;
  const int tcm  = (1 << tclog) - 1;

#pragma unroll
  for (int i = 0; i < 16; ++i) {
    int fidx = (i * 256 + tid) * 4;
    int row = fidx >> 7, k = fidx & 127;
    long cr = m0 + row;
    long b  = cr >> tclog;
    long tl = cr & tcm;
    f32x4 v = *(const f32x4*)(x + ((size_t)b * 512 + t0 + tl) * 128 + k);
    ushort4 pk;
    pk.x = f2h(v[0]); pk.y = f2h(v[1]); pk.z = f2h(v[2]); pk.w = f2h(v[3]);
    int byte = (row * 256 + k * 2) ^ ((row & 7) << 4);
    *(ushort4*)((char*)Ash + byte) = pk;
  }

  const int mh = (wv >> 1) * 64;
  const int nh = (wv & 1) * 64;

  for (int nc = 0; nc < 8; ++nc) {
    __syncthreads();
    {
      const char* wb = (const char*)(wih + nc * 128 * 128);
#pragma unroll
      for (int i = 0; i < 8; ++i) {
        int idx16 = i * 256 + tid;
        int row = idx16 >> 4, ch = idx16 & 15;
        int srcoff = row * 256 + ((ch * 16) ^ ((row & 7) << 4));
        u32x4 v = *(const u32x4*)(wb + srcoff);
        *(u32x4*)((char*)Bsh + idx16 * 16) = v;
      }
    }
    __syncthreads();

    float bias_v[4];
#pragma unroll
    for (int nt = 0; nt < 4; ++nt)
      bias_v[nt] = bconv[nc * 128 + nh + nt * 16 + c16];

    f16x8 af[4][4], bfr[4][4];
#pragma unroll
    for (int sm = 0; sm < 4; ++sm)
#pragma unroll
      for (int kt = 0; kt < 4; ++kt) {
        int m = mh + sm * 16 + c16;
        int byte = (m * 256 + (kt * 32 + gq * 8) * 2) ^ ((m & 7) << 4);
        af[sm][kt] = __builtin_bit_cast(f16x8, *(const u32x4*)((const char*)Ash + byte));
      }
#pragma unroll
    for (int nt = 0; nt < 4; ++nt)
#pragma unroll
      for (int kt = 0; kt < 4; ++kt) {
        int n = nh + nt * 16 + c16;
        int byte = (n * 256 + (kt * 32 + gq * 8) * 2) ^ ((n & 7) << 4);
        bfr[nt][kt] = __builtin_bit_cast(f16x8, *(const u32x4*)((const char*)Bsh + byte));
      }

    f32x4 acc[4][4];
#pragma unroll
    for (int sm = 0; sm < 4; ++sm)
#pragma unroll
      for (int nt = 0; nt < 4; ++nt) { f32x4 z = {0.f, 0.f, 0.f, 0.f}; acc[sm][nt] = z; }
#pragma unroll
    for (int sm = 0; sm < 4; ++sm)
#pragma unroll
      for (int nt = 0; nt < 4; ++nt)
#pragma unroll
        for (int kt = 0; kt < 4; ++kt)
          acc[sm][nt] = __builtin_amdgcn_mfma_f32_16x16x32_f16(af[sm][kt], bfr[nt][kt], acc[sm][nt], 0, 0, 0);

#pragma unroll
    for (int sm = 0; sm < 4; ++sm)
#pragma unroll
      for (int nt = 0; nt < 4; ++nt) {
        long row = m0 + mh + sm * 16 + gq * 4;
        int gcol = nc * 128 + nh + nt * 16 + c16;
#pragma unroll
        for (int r = 0; r < 4; ++r)
          xg[(size_t)(row + r) * 1024 + gcol] = f2h(acc[sm][nt][r] + bias_v[nt]);
      }
  }
}

// ---------------------------------------------------------------- fused kernel
// blocks 0-127: lstm chunk c (4 batch rows each). blocks 128-255: xgemm c+1.
__global__ __launch_bounds__(512)
void fused_chunk(
    const unsigned short* __restrict__ xgc, const signed char* __restrict__ wq,
    const float* __restrict__ scales, signed char* __restrict__ hst,
    float* __restrict__ cst, float* __restrict__ out, int Tc, int first, int last,
    const float* __restrict__ x, const unsigned short* __restrict__ wih,
    const float* __restrict__ bconv, unsigned short* __restrict__ xgn,
    int t0n, int tclog, int do_x) {
  __shared__ char smem[65536];

  const int tid  = threadIdx.x;
  const int lane = tid & 63;
  const int wv   = tid >> 6;      // 0..7
  const int c16  = lane & 15;
  const int gq   = lane >> 4;     // 0..3

  if (blockIdx.x < 128) {
    // ------------------------------ LSTM: 4 batch rows, M-rows {0,4,8,12}
    // h buffer: [2][4 rows x 288B stride] i8 (288/4=72 dwords; 72%32=8 ->
    // the 4 rows' 8-dword write spans land on disjoint banks).
    signed char (*hb)[1152] = (signed char (*)[1152])smem;
    const int b0 = blockIdx.x * 4;

    // lane's two output cols are ADJACENT: colA = wv*32 + 2*c16, colB = +1
    const int colA = wv * 32 + 2 * c16;
    float2 cv = *(const float2*)&cst[(b0 + gq) * 256 + colA];

    const float sw   = scales[0] * (1.0f / 127.0f);
    const float facR = sw * (1.0f / 127.0f);
    const float fac0 = first ? sw * (scales[1] * (1.0f / 127.0f)) : facR;

    // weights (pre-permuted in prep2): position n = g*256+wv*32+ntc*16+c16
    // holds actual col 2*c16+ntc. nt = g*2+ntc.
    i32x4 wf[8][4];
#pragma unroll
    for (int nt = 0; nt < 8; ++nt)
#pragma unroll
      for (int kt = 0; kt < 4; ++kt) {
        int n = (nt >> 1) * 256 + wv * 32 + (nt & 1) * 16 + c16;
        wf[nt][kt] = *(const i32x4*)(wq + n * 256 + kt * 64 + gq * 16);
      }
#pragma unroll
    for (int nt = 0; nt < 8; ++nt)
#pragma unroll
      for (int kt = 0; kt < 4; ++kt)
        asm volatile("" : "+v"(wf[nt][kt]));
    asm volatile("" ::: "memory");

    // init hb[0]: rows 0..3 (stride 288B), cols 0..255 (plain order)
    for (int i = tid; i < 1024; i += 512) {
      int row = i >> 8, cc = i & 255;
      hb[0][row * 288 + cc] = hst[(b0 + row) * 256 + cc];
    }

    // per-lane xg: [row][tt][col*4+gate]; colA,colB adjacent -> ONE dwordx4:
    // v[0]=(iA|fA<<16) v[1]=(gA|oA<<16) v[2]=(iB|fB<<16) v[3]=(gB|oB<<16)
    const char* pxp = (const char*)xgc +
        (((size_t)(b0 + gq) * Tc) * 1024 + (size_t)colA * 4) * 2;
    u32x4 px = *(const u32x4*)pxp;
    pxp += 2048;

    const bool mrow = (c16 & 3) == 0;  // A-lanes: M-rows 0,4,8,12
    const int  hrow = c16 >> 2;
    i32x4 af[4];
#pragma unroll
    for (int kt = 0; kt < 4; ++kt) { i32x4 z = {0, 0, 0, 0}; af[kt] = z; }
    const i32x4 zacc = {0, 0, 0, 0};
    unsigned short hpack = 0;

    __syncthreads();

    for (int tt = 0; tt < Tc; ++tt) {
      const int cur = tt & 1;

      if (mrow) {
        const signed char* hp = &hb[cur][hrow * 288 + gq * 16];
        af[0] = *(const i32x4*)(hp);
        af[1] = *(const i32x4*)(hp + 64);
        af[2] = *(const i32x4*)(hp + 128);
        af[3] = *(const i32x4*)(hp + 192);
      }

      // prefetch next step's xg (last iter reads adjacent ws region; unused)
      u32x4 pn = *(const u32x4*)pxp;
      pxp += 2048;

      i32x4 acc[8];
      // even accs (colA outputs) first: unblock elementwise-A early
#pragma unroll
      for (int ne = 0; ne < 4; ++ne)
        acc[2 * ne] = __builtin_amdgcn_mfma_i32_16x16x64_i8(af[0], wf[2 * ne][0], zacc, 0, 0, 0);
#pragma unroll
      for (int kt = 1; kt < 4; ++kt)
#pragma unroll
        for (int ne = 0; ne < 4; ++ne)
          acc[2 * ne] = __builtin_amdgcn_mfma_i32_16x16x64_i8(af[kt], wf[2 * ne][kt], acc[2 * ne], 0, 0, 0);
#pragma unroll
      for (int ne = 0; ne < 4; ++ne)
        acc[2 * ne + 1] = __builtin_amdgcn_mfma_i32_16x16x64_i8(af[0], wf[2 * ne + 1][0], zacc, 0, 0, 0);
#pragma unroll
      for (int kt = 1; kt < 4; ++kt)
#pragma unroll
        for (int ne = 0; ne < 4; ++ne)
          acc[2 * ne + 1] = __builtin_amdgcn_mfma_i32_16x16x64_i8(af[kt], wf[2 * ne + 1][kt], acc[2 * ne + 1], 0, 0, 0);

      const float fac = (tt == 0) ? fac0 : facR;

      int q0, q1;
      {  // colA
        float gi = __builtin_fmaf((float)acc[0][0], fac, h2f((unsigned short)(px[0] & 0xffff)));
        float gf = __builtin_fmaf((float)acc[2][0], fac, h2f((unsigned short)(px[0] >> 16)));
        float gg = __builtin_fmaf((float)acc[4][0], fac, h2f((unsigned short)(px[1] & 0xffff)));
        float go = __builtin_fmaf((float)acc[6][0], fac, h2f((unsigned short)(px[1] >> 16)));
        cv.x = fast_sigmoid(gf) * cv.x + fast_sigmoid(gi) * fast_tanh(gg);
        float hn = fast_sigmoid(go) * fast_tanh(cv.x);
        q0 = (int)rintf(hn * 127.0f);
      }
      {  // colB
        float gi = __builtin_fmaf((float)acc[1][0], fac, h2f((unsigned short)(px[2] & 0xffff)));
        float gf = __builtin_fmaf((float)acc[3][0], fac, h2f((unsigned short)(px[2] >> 16)));
        float gg = __builtin_fmaf((float)acc[5][0], fac, h2f((unsigned short)(px[3] & 0xffff)));
        float go = __builtin_fmaf((float)acc[7][0], fac, h2f((unsigned short)(px[3] >> 16)));
        cv.y = fast_sigmoid(gf) * cv.y + fast_sigmoid(gi) * fast_tanh(gg);
        float hn = fast_sigmoid(go) * fast_tanh(cv.y);
        q1 = (int)rintf(hn * 127.0f);
      }
      hpack = (unsigned short)((q0 & 0xff) | ((q1 & 0xff) << 8));
      *(unsigned short*)&hb[cur ^ 1][gq * 288 + colA] = hpack;

      px = pn;
      __syncthreads();
    }

    *(float2*)&cst[(b0 + gq) * 256 + colA] = cv;
    *(unsigned short*)&hst[(b0 + gq) * 256 + colA] = hpack;
    if (last) {
      *(float2*)&out[(b0 + gq) * 256 + colA] = cv;
    }
  } else if (do_x) {
    // ------------------------------ XGEMM for chunk c+1 (512 threads/tile)
    unsigned short* Ash = (unsigned short*)smem;            // 128x128 f16
    unsigned short* Bsh = (unsigned short*)(smem + 32768);  // 128x128 f16
    const int tcm    = (1 << tclog) - 1;
    const int ntiles = Tc << 2;          // (512*Tc)/128
    const int wm = wv >> 2, wn = wv & 3; // 2x4 wave grid
    const int mh = wm * 64, nh = wn * 32;

    for (int rt = (int)blockIdx.x - 128; rt < ntiles; rt += 128) {
      const long m0 = (long)rt * 128;
      __syncthreads();  // previous tile's readers done before re-staging

#pragma unroll
      for (int i = 0; i < 8; ++i) {
        int fidx = (i * 512 + tid) * 4;
        int row = fidx >> 7, k = fidx & 127;
        long cr = m0 + row;
        long b  = cr >> tclog;
        long tl = cr & tcm;
        f32x4 v = *(const f32x4*)(x + ((size_t)b * 512 + t0n + tl) * 128 + k);
        ushort4 pk;
        pk.x = f2h(v[0]); pk.y = f2h(v[1]); pk.z = f2h(v[2]); pk.w = f2h(v[3]);
        int byte = (row * 256 + k * 2) ^ ((row & 7) << 4);
        *(ushort4*)((char*)Ash + byte) = pk;
      }

      for (int nc = 0; nc < 8; ++nc) {
        __syncthreads();
        {
          const char* wb = (const char*)(wih + nc * 128 * 128);
#pragma unroll
          for (int i = 0; i < 4; ++i) {
            int idx16 = i * 512 + tid;
            int row = idx16 >> 4, ch = idx16 & 15;
            int srcoff = row * 256 + ((ch * 16) ^ ((row & 7) << 4));
            u32x4 v = *(const u32x4*)(wb + srcoff);
            *(u32x4*)((char*)Bsh + idx16 * 16) = v;
          }
        }
        __syncthreads();

        float bias_v[2];
#pragma unroll
        for (int nt = 0; nt < 2; ++nt)
          bias_v[nt] = bconv[nc * 128 + nh + nt * 16 + c16];

        f16x8 af[4][4], bfr[2][4];
#pragma unroll
        for (int sm = 0; sm < 4; ++sm)
#pragma unroll
          for (int kt = 0; kt < 4; ++kt) {
            int m = mh + sm * 16 + c16;
            int byte = (m * 256 + (kt * 32 + gq * 8) * 2) ^ ((m & 7) << 4);
            af[sm][kt] = __builtin_bit_cast(f16x8, *(const u32x4*)((const char*)Ash + byte));
          }
#pragma unroll
        for (int nt = 0; nt < 2; ++nt)
#pragma unroll
          for (int kt = 0; kt < 4; ++kt) {
            int n = nh + nt * 16 + c16;
            int byte = (n * 256 + (kt * 32 + gq * 8) * 2) ^ ((n & 7) << 4);
            bfr[nt][kt] = __builtin_bit_cast(f16x8, *(const u32x4*)((const char*)Bsh + byte));
          }

        f32x4 acc[4][2];
#pragma unroll
        for (int sm = 0; sm < 4; ++sm)
#pragma unroll
          for (int nt = 0; nt < 2; ++nt) { f32x4 z = {0.f, 0.f, 0.f, 0.f}; acc[sm][nt] = z; }
#pragma unroll
        for (int sm = 0; sm < 4; ++sm)
#pragma unroll
          for (int nt = 0; nt < 2; ++nt)
#pragma unroll
            for (int kt = 0; kt < 4; ++kt)
              acc[sm][nt] = __builtin_amdgcn_mfma_f32_16x16x32_f16(af[sm][kt], bfr[nt][kt], acc[sm][nt], 0, 0, 0);

#pragma unroll
        for (int sm = 0; sm < 4; ++sm)
#pragma unroll
          for (int nt = 0; nt < 2; ++nt) {
            long row = m0 + mh + sm * 16 + gq * 4;
            int gcol = nc * 128 + nh + nt * 16 + c16;
#pragma unroll
            for (int r = 0; r < 4; ++r)
              xgn[(size_t)(row + r) * 1024 + gcol] = f2h(acc[sm][nt][r] + bias_v[nt]);
          }
      }
    }
  }
}

// ---------------------------------------------------------------- launch
extern "C" void kernel_launch(void* const* d_in, const int* in_sizes, int n_in,
                              void* d_out, int out_size, void* d_ws, size_t ws_size,
                              hipStream_t stream) {
  const float* x   = (const float*)d_in[0];
  const float* h0  = (const float*)d_in[1];
  const float* c0  = (const float*)d_in[2];
  const float* wih = (const float*)d_in[3];
  const float* whh = (const float*)d_in[4];
  const float* bih = (const float*)d_in[5];
  const float* bhh = (const float*)d_in[6];
  float* out = (float*)d_out;

  const size_t fixed = 262144u /*wih f16*/ + 262144u /*wq*/ + 131072u /*hst*/
                     + 524288u /*cst*/ + 4096u /*bconv*/ + 1024u /*scales*/;
  int tc = 128;  // ws_size caps 2 xg buffers at 2x134MB -> tc=128, NC=4
  while (tc > 4 && 2u * (size_t)512 * tc * 2048 + fixed > ws_size) tc >>= 1;
  int tclog = 31 - __builtin_clz((unsigned)tc);
  size_t bufsz = (size_t)512 * tc * 2048;

  char* ws = (char*)d_ws;
  unsigned short* xgb0  = (unsigned short*)ws;
  unsigned short* xgb1  = (unsigned short*)(ws + bufsz);
  size_t off = 2u * bufsz;
  unsigned short* wih_h = (unsigned short*)(ws + off);  off += 262144u;
  signed char*    wqb   = (signed char*)(ws + off);     off += 262144u;
  signed char*    hst   = (signed char*)(ws + off);     off += 131072u;
  float*          cst   = (float*)(ws + off);           off += 524288u;
  float*          bcv   = (float*)(ws + off);           off += 4096u;
  float*          scl   = (float*)(ws + off);

  prep1<<<320, 256, 0, stream>>>(whh, h0, wih, bih, bhh, scl, wih_h, bcv);
  prep2<<<256, 256, 0, stream>>>(whh, h0, c0, scl, wqb, hst, cst);

  // prologue: xgemm for chunk 0 (full chip)
  xgemm<<<4 * tc, 256, 0, stream>>>(x, wih_h, bcv, xgb0, 0, tclog);

  int NC = 512 / tc;
  for (int c = 0; c < NC; ++c) {
    unsigned short* cur = (c & 1) ? xgb1 : xgb0;
    unsigned short* nxt = (c & 1) ? xgb0 : xgb1;
    int do_x = (c + 1 < NC) ? 1 : 0;
    fused_chunk<<<256, 512, 0, stream>>>(
        cur, wqb, scl, hst, cst, out, tc, (c == 0) ? 1 : 0, (c == NC - 1) ? 1 : 0,
        x, wih_h, bcv, nxt, (c + 1) * tc, tclog, do_x);
  }
}

// Round 11
// 522.584 us; speedup vs baseline: 1.0503x; 1.0069x over previous
//
#include <hip/hip_runtime.h>
#include <hip/hip_bf16.h>
#include <hip/hip_fp16.h>

// LSTM: B=512, T=512, I=128, H=256, gates G=4H=1024 (PyTorch i,f,g,o order).
// Round-11: lstm blocks go 1024-thread (16 waves, 4/SIMD). Wave wv owns h-cols
// [wv*16, wv*16+16); each lane holds w_hh i8 frags for its col x 4 gates in
// 64 VGPRs (wf[4][4]) and computes exactly ONE output/step (acc[g][0]).
// Keeps R=4 blocks=128 (matrix wall 1306 cyc/step/CU) while halving the
// elementwise issue+chain per wave vs the 2-output layout (2570 -> ~2100).
// xgemm(c+1) co-runs on blocks 128-255, retiled for 1024 threads.

typedef __attribute__((ext_vector_type(4))) float f32x4;
typedef __attribute__((ext_vector_type(8))) _Float16 f16x8;
typedef __attribute__((ext_vector_type(4))) unsigned int u32x4;
typedef __attribute__((ext_vector_type(4))) int i32x4;

static __device__ __forceinline__ float h2f(unsigned short u) {
  return (float)__builtin_bit_cast(_Float16, u);
}
static __device__ __forceinline__ unsigned short f2h(float f) {
  return __builtin_bit_cast(unsigned short, (_Float16)f);
}
static __device__ __forceinline__ float fast_sigmoid(float x) {
  return __builtin_amdgcn_rcpf(1.0f + __builtin_amdgcn_exp2f(-1.44269504f * x));
}
static __device__ __forceinline__ float fast_tanh(float x) {
  return 1.0f - 2.0f * __builtin_amdgcn_rcpf(1.0f + __builtin_amdgcn_exp2f(2.88539008f * x));
}

// ---------------------------------------------------------------- prep kernels
// scl layout (floats): [0]=sw, [1]=sh, [8..135] whh partials, [136..199] h0.
__global__ __launch_bounds__(256) void prep1(
    const float* __restrict__ whh, const float* __restrict__ h0,
    const float* __restrict__ wih, const float* __restrict__ bih,
    const float* __restrict__ bhh,
    float* __restrict__ scl, unsigned short* __restrict__ wih_h,
    float* __restrict__ bcv) {
  const int b = blockIdx.x, tid = threadIdx.x;
  if (b < 192) {
    __shared__ float s[256];
    const float* src = (b < 128) ? whh : h0;
    int base = (b < 128) ? b * 2048 : (b - 128) * 2048;
    float m = 0.f;
#pragma unroll
    for (int i = 0; i < 8; ++i) m = fmaxf(m, fabsf(src[base + i * 256 + tid]));
    s[tid] = m; __syncthreads();
    for (int w = 128; w > 0; w >>= 1) {
      if (tid < w) s[tid] = fmaxf(s[tid], s[tid + w]);
      __syncthreads();
    }
    if (tid == 0) scl[8 + b] = s[0];
  } else {
    // w_ih cast + gate-row interleave: dst row q <- src row (q&3)*256 + (q>>2)
    int i = ((b - 192) * 256 + tid) * 4;  // over 131072
    int q = i >> 7, k = i & 127;
    int p = (q & 3) * 256 + (q >> 2);
    f32x4 v = *(const f32x4*)(wih + p * 128 + k);
    ushort4 pk;
    pk.x = f2h(v[0]); pk.y = f2h(v[1]); pk.z = f2h(v[2]); pk.w = f2h(v[3]);
    *(ushort4*)(wih_h + i) = pk;
    if (b == 192) {
      for (int q2 = tid; q2 < 1024; q2 += 256) {
        int p2 = (q2 & 3) * 256 + (q2 >> 2);
        bcv[q2] = bih[p2] + bhh[p2];
      }
    }
  }
}

__global__ __launch_bounds__(256) void prep2(
    const float* __restrict__ whh, const float* __restrict__ h0,
    const float* __restrict__ c0, float* __restrict__ scl,
    signed char* __restrict__ wq, signed char* __restrict__ hst,
    float* __restrict__ cst) {
  __shared__ float s[256];
  const int b = blockIdx.x, tid = threadIdx.x;
  float v = (tid < 128) ? scl[8 + tid] : 0.f;
  s[tid] = v; __syncthreads();
  for (int w = 128; w > 0; w >>= 1) {
    if (tid < w) s[tid] = fmaxf(s[tid], s[tid + w]);
    __syncthreads();
  }
  float sw = s[0]; __syncthreads();
  v = (tid < 64) ? scl[136 + tid] : 0.f;
  s[tid] = v; __syncthreads();
  for (int w = 128; w > 0; w >>= 1) {
    if (tid < w) s[tid] = fmaxf(s[tid], s[tid + w]);
    __syncthreads();
  }
  float sh = s[0];
  if (b == 0 && tid == 0) { scl[0] = sw; scl[1] = sh; }

  // quantize w_hh (plain layout: row n = gate*256 + col)
  const float invw = 127.0f / sw;
  int base = b * 1024;
#pragma unroll
  for (int i = 0; i < 4; ++i) {
    int idx = base + i * 256 + tid;
    int q = (int)rintf(whh[idx] * invw);
    wq[idx] = (signed char)max(-127, min(127, q));
  }
  // state init
  const float invh = 127.0f / sh;
  int sb = b * 512;
#pragma unroll
  for (int i = 0; i < 2; ++i) {
    int idx = sb + i * 256 + tid;
    int q = (int)rintf(h0[idx] * invh);
    hst[idx] = (signed char)max(-127, min(127, q));
    cst[idx] = c0[idx];
  }
}

// ---------------------------------------------------------------- prologue gemm
__global__ __launch_bounds__(256) void xgemm(
    const float* __restrict__ x, const unsigned short* __restrict__ wih,
    const float* __restrict__ bconv,
    unsigned short* __restrict__ xg, int t0, int tclog) {
  __shared__ unsigned short Ash[128 * 128];
  __shared__ unsigned short Bsh[128 * 128];

  const int tid  = threadIdx.x;
  const int lane = tid & 63;
  const int wv   = tid >> 6;
  const int c16  = lane & 15;
  const int gq   = lane >> 4;
  const long m0  = (long)blockIdx.x * 128;
  const int tcm  = (1 << tclog) - 1;

#pragma unroll
  for (int i = 0; i < 16; ++i) {
    int fidx = (i * 256 + tid) * 4;
    int row = fidx >> 7, k = fidx & 127;
    long cr = m0 + row;
    long b  = cr >> tclog;
    long tl = cr & tcm;
    f32x4 v = *(const f32x4*)(x + ((size_t)b * 512 + t0 + tl) * 128 + k);
    ushort4 pk;
    pk.x = f2h(v[0]); pk.y = f2h(v[1]); pk.z = f2h(v[2]); pk.w = f2h(v[3]);
    int byte = (row * 256 + k * 2) ^ ((row & 7) << 4);
    *(ushort4*)((char*)Ash + byte) = pk;
  }

  const int mh = (wv >> 1) * 64;
  const int nh = (wv & 1) * 64;

  for (int nc = 0; nc < 8; ++nc) {
    __syncthreads();
    {
      const char* wb = (const char*)(wih + nc * 128 * 128);
#pragma unroll
      for (int i = 0; i < 8; ++i) {
        int idx16 = i * 256 + tid;
        int row = idx16 >> 4, ch = idx16 & 15;
        int srcoff = row * 256 + ((ch * 16) ^ ((row & 7) << 4));
        u32x4 v = *(const u32x4*)(wb + srcoff);
        *(u32x4*)((char*)Bsh + idx16 * 16) = v;
      }
    }
    __syncthreads();

    float bias_v[4];
#pragma unroll
    for (int nt = 0; nt < 4; ++nt)
      bias_v[nt] = bconv[nc * 128 + nh + nt * 16 + c16];

    f16x8 af[4][4], bfr[4][4];
#pragma unroll
    for (int sm = 0; sm < 4; ++sm)
#pragma unroll
      for (int kt = 0; kt < 4; ++kt) {
        int m = mh + sm * 16 + c16;
        int byte = (m * 256 + (kt * 32 + gq * 8) * 2) ^ ((m & 7) << 4);
        af[sm][kt] = __builtin_bit_cast(f16x8, *(const u32x4*)((const char*)Ash + byte));
      }
#pragma unroll
    for (int nt = 0; nt < 4; ++nt)
#pragma unroll
      for (int kt = 0; kt < 4; ++kt) {
        int n = nh + nt * 16 + c16;
        int byte = (n * 256 + (kt * 32 + gq * 8) * 2) ^ ((n & 7) << 4);
        bfr[nt][kt] = __builtin_bit_cast(f16x8, *(const u32x4*)((const char*)Bsh + byte));
      }

    f32x4 acc[4][4];
#pragma unroll
    for (int sm = 0; sm < 4; ++sm)
#pragma unroll
      for (int nt = 0; nt < 4; ++nt) { f32x4 z = {0.f, 0.f, 0.f, 0.f}; acc[sm][nt] = z; }
#pragma unroll
    for (int sm = 0; sm < 4; ++sm)
#pragma unroll
      for (int nt = 0; nt < 4; ++nt)
#pragma unroll
        for (int kt = 0; kt < 4; ++kt)
          acc[sm][nt] = __builtin_amdgcn_mfma_f32_16x16x32_f16(af[sm][kt], bfr[nt][kt], acc[sm][nt], 0, 0, 0);

#pragma unroll
    for (int sm = 0; sm < 4; ++sm)
#pragma unroll
      for (int nt = 0; nt < 4; ++nt) {
        long row = m0 + mh + sm * 16 + gq * 4;
        int gcol = nc * 128 + nh + nt * 16 + c16;
#pragma unroll
        for (int r = 0; r < 4; ++r)
          xg[(size_t)(row + r) * 1024 + gcol] = f2h(acc[sm][nt][r] + bias_v[nt]);
      }
  }
}

// ---------------------------------------------------------------- fused kernel
// 1024 threads. blocks 0-127: lstm chunk c (4 rows, 16 waves, 1 output/lane).
// blocks 128-255: xgemm chunk c+1 (16-wave tiling).
__global__ __launch_bounds__(1024)
void fused_chunk(
    const unsigned short* __restrict__ xgc, const signed char* __restrict__ wq,
    const float* __restrict__ scales, signed char* __restrict__ hst,
    float* __restrict__ cst, float* __restrict__ out, int Tc, int first, int last,
    const float* __restrict__ x, const unsigned short* __restrict__ wih,
    const float* __restrict__ bconv, unsigned short* __restrict__ xgn,
    int t0n, int tclog, int do_x) {
  __shared__ char smem[65536];

  const int tid  = threadIdx.x;
  const int lane = tid & 63;
  const int wv   = tid >> 6;      // 0..15
  const int c16  = lane & 15;
  const int gq   = lane >> 4;     // 0..3

  if (blockIdx.x < 128) {
    // ------------------------------ LSTM: rows 0..3 at M-rows {0,4,8,12}
    signed char (*hb)[1152] = (signed char (*)[1152])smem;  // [buf][4 x 288B]
    const int b0 = blockIdx.x * 4;
    const int col = wv * 16 + c16;          // this lane's single output col
    float cv = cst[(b0 + gq) * 256 + col];  // output row = gq

    const float sw   = scales[0] * (1.0f / 127.0f);
    const float facR = sw * (1.0f / 127.0f);
    const float fac0 = first ? sw * (scales[1] * (1.0f / 127.0f)) : facR;

    // weights: gate g, n = g*256 + col, k = kt*64 + gq*16 -> 64 VGPR total
    i32x4 wf[4][4];
#pragma unroll
    for (int g = 0; g < 4; ++g)
#pragma unroll
      for (int kt = 0; kt < 4; ++kt)
        wf[g][kt] = *(const i32x4*)(wq + (g * 256 + col) * 256 + kt * 64 + gq * 16);
#pragma unroll
    for (int g = 0; g < 4; ++g)
#pragma unroll
      for (int kt = 0; kt < 4; ++kt)
        asm volatile("" : "+v"(wf[g][kt]));

    // init hb[0]: rows 0..3 (stride 288B), cols 0..255
    {
      int row = tid >> 8, cc = tid & 255;
      hb[0][row * 288 + cc] = hst[(b0 + row) * 256 + cc];
    }

    // per-lane xg: [row=gq][t][col*4 + gate], 8 B/lane/step
    const char* pxp = (const char*)xgc +
        (((size_t)(b0 + gq) * Tc) * 1024 + (size_t)col * 4) * 2;
    uint2 px = *(const uint2*)pxp;
    pxp += 2048;

    const bool mrow = (c16 & 3) == 0;  // A-lanes: M-rows 0,4,8,12
    const int  hrow = c16 >> 2;
    i32x4 af[4];
#pragma unroll
    for (int kt = 0; kt < 4; ++kt) { i32x4 z = {0, 0, 0, 0}; af[kt] = z; }
    const i32x4 zacc = {0, 0, 0, 0};
    int qlast = 0;

    __syncthreads();

    for (int tt = 0; tt < Tc; ++tt) {
      const int cur = tt & 1;

      if (mrow) {
        const signed char* hp = &hb[cur][hrow * 288 + gq * 16];
        af[0] = *(const i32x4*)(hp);
        af[1] = *(const i32x4*)(hp + 64);
        af[2] = *(const i32x4*)(hp + 128);
        af[3] = *(const i32x4*)(hp + 192);
      }

      // prefetch next step's xg (last iter reads adjacent ws region; unused)
      uint2 pn = *(const uint2*)pxp;
      pxp += 2048;

      // depth-first per gate, order g(2), i(0), f(1), o(3): the cell-gate's
      // tanh chain (longest) can start while o's MFMAs still execute.
      i32x4 acc[4];
      {
        const int go_[4] = {2, 0, 1, 3};
#pragma unroll
        for (int gi_ = 0; gi_ < 4; ++gi_) {
          const int g = go_[gi_];
          acc[g] = __builtin_amdgcn_mfma_i32_16x16x64_i8(af[0], wf[g][0], zacc, 0, 0, 0);
#pragma unroll
          for (int kt = 1; kt < 4; ++kt)
            acc[g] = __builtin_amdgcn_mfma_i32_16x16x64_i8(af[kt], wf[g][kt], acc[g], 0, 0, 0);
        }
      }

      const float fac = (tt == 0) ? fac0 : facR;

      // D: lane (c16,gq) reg 0 = row gq*4 (batch row gq), col = this lane's col
      float xi  = h2f((unsigned short)(px.x & 0xffff));
      float xf  = h2f((unsigned short)(px.x >> 16));
      float xgv = h2f((unsigned short)(px.y & 0xffff));
      float xo  = h2f((unsigned short)(px.y >> 16));
      float gi = __builtin_fmaf((float)acc[0][0], fac, xi);
      float gf = __builtin_fmaf((float)acc[1][0], fac, xf);
      float gg = __builtin_fmaf((float)acc[2][0], fac, xgv);
      float go = __builtin_fmaf((float)acc[3][0], fac, xo);
      cv = fast_sigmoid(gf) * cv + fast_sigmoid(gi) * fast_tanh(gg);
      float hn = fast_sigmoid(go) * fast_tanh(cv);
      qlast = (int)rintf(hn * 127.0f);    // |hn| < 1 -> no clamp needed
      hb[cur ^ 1][gq * 288 + col] = (signed char)qlast;

      px = pn;
      __syncthreads();
    }

    cst[(b0 + gq) * 256 + col] = cv;
    hst[(b0 + gq) * 256 + col] = (signed char)qlast;
    if (last) out[(b0 + gq) * 256 + col] = cv;
  } else if (do_x) {
    // ------------------------------ XGEMM chunk c+1 (1024 thr, 16 waves)
    unsigned short* Ash = (unsigned short*)smem;            // 128x128 f16
    unsigned short* Bsh = (unsigned short*)(smem + 32768);  // 128x128 f16
    const int tcm    = (1 << tclog) - 1;
    const int ntiles = Tc << 2;            // (512*Tc)/128
    const int wm = wv >> 2, wn = wv & 3;   // 4x4 wave grid
    const int mh = wm * 32, nh = wn * 32;

    for (int rt = (int)blockIdx.x - 128; rt < ntiles; rt += 128) {
      const long m0 = (long)rt * 128;
      __syncthreads();  // previous tile's readers done before re-staging

      // stage A: 128x128 f32 -> f16, swizzled (4 iters x 1024 thr x 4 elems)
#pragma unroll
      for (int i = 0; i < 4; ++i) {
        int fidx = (i * 1024 + tid) * 4;
        int row = fidx >> 7, k = fidx & 127;
        long cr = m0 + row;
        long b  = cr >> tclog;
        long tl = cr & tcm;
        f32x4 v = *(const f32x4*)(x + ((size_t)b * 512 + t0n + tl) * 128 + k);
        ushort4 pk;
        pk.x = f2h(v[0]); pk.y = f2h(v[1]); pk.z = f2h(v[2]); pk.w = f2h(v[3]);
        int byte = (row * 256 + k * 2) ^ ((row & 7) << 4);
        *(ushort4*)((char*)Ash + byte) = pk;
      }

      for (int nc = 0; nc < 8; ++nc) {
        __syncthreads();
        {
          const char* wb = (const char*)(wih + nc * 128 * 128);
#pragma unroll
          for (int i = 0; i < 2; ++i) {
            int idx16 = i * 1024 + tid;
            int row = idx16 >> 4, ch = idx16 & 15;
            int srcoff = row * 256 + ((ch * 16) ^ ((row & 7) << 4));
            u32x4 v = *(const u32x4*)(wb + srcoff);
            *(u32x4*)((char*)Bsh + idx16 * 16) = v;
          }
        }
        __syncthreads();

        float bias_v[2];
#pragma unroll
        for (int nt = 0; nt < 2; ++nt)
          bias_v[nt] = bconv[nc * 128 + nh + nt * 16 + c16];

        f16x8 af[2][4], bfr[2][4];
#pragma unroll
        for (int sm = 0; sm < 2; ++sm)
#pragma unroll
          for (int kt = 0; kt < 4; ++kt) {
            int m = mh + sm * 16 + c16;
            int byte = (m * 256 + (kt * 32 + gq * 8) * 2) ^ ((m & 7) << 4);
            af[sm][kt] = __builtin_bit_cast(f16x8, *(const u32x4*)((const char*)Ash + byte));
          }
#pragma unroll
        for (int nt = 0; nt < 2; ++nt)
#pragma unroll
          for (int kt = 0; kt < 4; ++kt) {
            int n = nh + nt * 16 + c16;
            int byte = (n * 256 + (kt * 32 + gq * 8) * 2) ^ ((n & 7) << 4);
            bfr[nt][kt] = __builtin_bit_cast(f16x8, *(const u32x4*)((const char*)Bsh + byte));
          }

        f32x4 acc[2][2];
#pragma unroll
        for (int sm = 0; sm < 2; ++sm)
#pragma unroll
          for (int nt = 0; nt < 2; ++nt) { f32x4 z = {0.f, 0.f, 0.f, 0.f}; acc[sm][nt] = z; }
#pragma unroll
        for (int sm = 0; sm < 2; ++sm)
#pragma unroll
          for (int nt = 0; nt < 2; ++nt)
#pragma unroll
            for (int kt = 0; kt < 4; ++kt)
              acc[sm][nt] = __builtin_amdgcn_mfma_f32_16x16x32_f16(af[sm][kt], bfr[nt][kt], acc[sm][nt], 0, 0, 0);

#pragma unroll
        for (int sm = 0; sm < 2; ++sm)
#pragma unroll
          for (int nt = 0; nt < 2; ++nt) {
            long row = m0 + mh + sm * 16 + gq * 4;
            int gcol = nc * 128 + nh + nt * 16 + c16;
#pragma unroll
            for (int r = 0; r < 4; ++r)
              xgn[(size_t)(row + r) * 1024 + gcol] = f2h(acc[sm][nt][r] + bias_v[nt]);
          }
      }
    }
  }
}

// ---------------------------------------------------------------- launch
extern "C" void kernel_launch(void* const* d_in, const int* in_sizes, int n_in,
                              void* d_out, int out_size, void* d_ws, size_t ws_size,
                              hipStream_t stream) {
  const float* x   = (const float*)d_in[0];
  const float* h0  = (const float*)d_in[1];
  const float* c0  = (const float*)d_in[2];
  const float* wih = (const float*)d_in[3];
  const float* whh = (const float*)d_in[4];
  const float* bih = (const float*)d_in[5];
  const float* bhh = (const float*)d_in[6];
  float* out = (float*)d_out;

  const size_t fixed = 262144u /*wih f16*/ + 262144u /*wq*/ + 131072u /*hst*/
                     + 524288u /*cst*/ + 4096u /*bconv*/ + 1024u /*scales*/;
  int tc = 128;  // ws_size caps 2 xg buffers at 2x134MB -> tc=128, NC=4
  while (tc > 4 && 2u * (size_t)512 * tc * 2048 + fixed > ws_size) tc >>= 1;
  int tclog = 31 - __builtin_clz((unsigned)tc);
  size_t bufsz = (size_t)512 * tc * 2048;

  char* ws = (char*)d_ws;
  unsigned short* xgb0  = (unsigned short*)ws;
  unsigned short* xgb1  = (unsigned short*)(ws + bufsz);
  size_t off = 2u * bufsz;
  unsigned short* wih_h = (unsigned short*)(ws + off);  off += 262144u;
  signed char*    wqb   = (signed char*)(ws + off);     off += 262144u;
  signed char*    hst   = (signed char*)(ws + off);     off += 131072u;
  float*          cst   = (float*)(ws + off);           off += 524288u;
  float*          bcv   = (float*)(ws + off);           off += 4096u;
  float*          scl   = (float*)(ws + off);

  prep1<<<320, 256, 0, stream>>>(whh, h0, wih, bih, bhh, scl, wih_h, bcv);
  prep2<<<256, 256, 0, stream>>>(whh, h0, c0, scl, wqb, hst, cst);

  // prologue: xgemm for chunk 0 (full chip)
  xgemm<<<4 * tc, 256, 0, stream>>>(x, wih_h, bcv, xgb0, 0, tclog);

  int NC = 512 / tc;
  for (int c = 0; c < NC; ++c) {
    unsigned short* cur = (c & 1) ? xgb1 : xgb0;
    unsigned short* nxt = (c & 1) ? xgb0 : xgb1;
    int do_x = (c + 1 < NC) ? 1 : 0;
    fused_chunk<<<256, 1024, 0, stream>>>(
        cur, wqb, scl, hst, cst, out, tc, (c == 0) ? 1 : 0, (c == NC - 1) ? 1 : 0,
        x, wih_h, bcv, nxt, (c + 1) * tc, tclog, do_x);
  }
}

// Round 12
// 468.167 us; speedup vs baseline: 1.1724x; 1.1162x over previous
//
#include <hip/hip_runtime.h>
#include <hip/hip_bf16.h>
#include <hip/hip_fp16.h>

// LSTM: B=512, T=512, I=128, H=256, gates G=4H=1024 (PyTorch i,f,g,o order).
// Round-12: issue-budget model closed (1306 MFMA + 540 EW + 215 LDS + ~400
// overhead = 2500 cyc/step measured). This round: s_setprio(1) around MFMA
// (T5; waves role-split dynamically at 4/SIMD), unroll-by-2 (kills px moves,
// cur flip, half the loop control). Bit-exact math vs R11.

typedef __attribute__((ext_vector_type(4))) float f32x4;
typedef __attribute__((ext_vector_type(8))) _Float16 f16x8;
typedef __attribute__((ext_vector_type(4))) unsigned int u32x4;
typedef __attribute__((ext_vector_type(4))) int i32x4;

static __device__ __forceinline__ float h2f(unsigned short u) {
  return (float)__builtin_bit_cast(_Float16, u);
}
static __device__ __forceinline__ unsigned short f2h(float f) {
  return __builtin_bit_cast(unsigned short, (_Float16)f);
}
static __device__ __forceinline__ float fast_sigmoid(float x) {
  return __builtin_amdgcn_rcpf(1.0f + __builtin_amdgcn_exp2f(-1.44269504f * x));
}
static __device__ __forceinline__ float fast_tanh(float x) {
  return 1.0f - 2.0f * __builtin_amdgcn_rcpf(1.0f + __builtin_amdgcn_exp2f(2.88539008f * x));
}

// ---------------------------------------------------------------- prep kernels
// scl layout (floats): [0]=sw, [1]=sh, [8..135] whh partials, [136..199] h0.
__global__ __launch_bounds__(256) void prep1(
    const float* __restrict__ whh, const float* __restrict__ h0,
    const float* __restrict__ wih, const float* __restrict__ bih,
    const float* __restrict__ bhh,
    float* __restrict__ scl, unsigned short* __restrict__ wih_h,
    float* __restrict__ bcv) {
  const int b = blockIdx.x, tid = threadIdx.x;
  if (b < 192) {
    __shared__ float s[256];
    const float* src = (b < 128) ? whh : h0;
    int base = (b < 128) ? b * 2048 : (b - 128) * 2048;
    float m = 0.f;
#pragma unroll
    for (int i = 0; i < 8; ++i) m = fmaxf(m, fabsf(src[base + i * 256 + tid]));
    s[tid] = m; __syncthreads();
    for (int w = 128; w > 0; w >>= 1) {
      if (tid < w) s[tid] = fmaxf(s[tid], s[tid + w]);
      __syncthreads();
    }
    if (tid == 0) scl[8 + b] = s[0];
  } else {
    // w_ih cast + gate-row interleave: dst row q <- src row (q&3)*256 + (q>>2)
    int i = ((b - 192) * 256 + tid) * 4;  // over 131072
    int q = i >> 7, k = i & 127;
    int p = (q & 3) * 256 + (q >> 2);
    f32x4 v = *(const f32x4*)(wih + p * 128 + k);
    ushort4 pk;
    pk.x = f2h(v[0]); pk.y = f2h(v[1]); pk.z = f2h(v[2]); pk.w = f2h(v[3]);
    *(ushort4*)(wih_h + i) = pk;
    if (b == 192) {
      for (int q2 = tid; q2 < 1024; q2 += 256) {
        int p2 = (q2 & 3) * 256 + (q2 >> 2);
        bcv[q2] = bih[p2] + bhh[p2];
      }
    }
  }
}

__global__ __launch_bounds__(256) void prep2(
    const float* __restrict__ whh, const float* __restrict__ h0,
    const float* __restrict__ c0, float* __restrict__ scl,
    signed char* __restrict__ wq, signed char* __restrict__ hst,
    float* __restrict__ cst) {
  __shared__ float s[256];
  const int b = blockIdx.x, tid = threadIdx.x;
  float v = (tid < 128) ? scl[8 + tid] : 0.f;
  s[tid] = v; __syncthreads();
  for (int w = 128; w > 0; w >>= 1) {
    if (tid < w) s[tid] = fmaxf(s[tid], s[tid + w]);
    __syncthreads();
  }
  float sw = s[0]; __syncthreads();
  v = (tid < 64) ? scl[136 + tid] : 0.f;
  s[tid] = v; __syncthreads();
  for (int w = 128; w > 0; w >>= 1) {
    if (tid < w) s[tid] = fmaxf(s[tid], s[tid + w]);
    __syncthreads();
  }
  float sh = s[0];
  if (b == 0 && tid == 0) { scl[0] = sw; scl[1] = sh; }

  // quantize w_hh (plain layout: row n = gate*256 + col)
  const float invw = 127.0f / sw;
  int base = b * 1024;
#pragma unroll
  for (int i = 0; i < 4; ++i) {
    int idx = base + i * 256 + tid;
    int q = (int)rintf(whh[idx] * invw);
    wq[idx] = (signed char)max(-127, min(127, q));
  }
  // state init
  const float invh = 127.0f / sh;
  int sb = b * 512;
#pragma unroll
  for (int i = 0; i < 2; ++i) {
    int idx = sb + i * 256 + tid;
    int q = (int)rintf(h0[idx] * invh);
    hst[idx] = (signed char)max(-127, min(127, q));
    cst[idx] = c0[idx];
  }
}

// ---------------------------------------------------------------- prologue gemm
__global__ __launch_bounds__(256) void xgemm(
    const float* __restrict__ x, const unsigned short* __restrict__ wih,
    const float* __restrict__ bconv,
    unsigned short* __restrict__ xg, int t0, int tclog) {
  __shared__ unsigned short Ash[128 * 128];
  __shared__ unsigned short Bsh[128 * 128];

  const int tid  = threadIdx.x;
  const int lane = tid & 63;
  const int wv   = tid >> 6;
  const int c16  = lane & 15;
  const int gq   = lane >> 4;
  const long m0  = (long)blockIdx.x * 128;
  const int tcm  = (1 << tclog) - 1;

#pragma unroll
  for (int i = 0; i < 16; ++i) {
    int fidx = (i * 256 + tid) * 4;
    int row = fidx >> 7, k = fidx & 127;
    long cr = m0 + row;
    long b  = cr >> tclog;
    long tl = cr & tcm;
    f32x4 v = *(const f32x4*)(x + ((size_t)b * 512 + t0 + tl) * 128 + k);
    ushort4 pk;
    pk.x = f2h(v[0]); pk.y = f2h(v[1]); pk.z = f2h(v[2]); pk.w = f2h(v[3]);
    int byte = (row * 256 + k * 2) ^ ((row & 7) << 4);
    *(ushort4*)((char*)Ash + byte) = pk;
  }

  const int mh = (wv >> 1) * 64;
  const int nh = (wv & 1) * 64;

  for (int nc = 0; nc < 8; ++nc) {
    __syncthreads();
    {
      const char* wb = (const char*)(wih + nc * 128 * 128);
#pragma unroll
      for (int i = 0; i < 8; ++i) {
        int idx16 = i * 256 + tid;
        int row = idx16 >> 4, ch = idx16 & 15;
        int srcoff = row * 256 + ((ch * 16) ^ ((row & 7) << 4));
        u32x4 v = *(const u32x4*)(wb + srcoff);
        *(u32x4*)((char*)Bsh + idx16 * 16) = v;
      }
    }
    __syncthreads();

    float bias_v[4];
#pragma unroll
    for (int nt = 0; nt < 4; ++nt)
      bias_v[nt] = bconv[nc * 128 + nh + nt * 16 + c16];

    f16x8 af[4][4], bfr[4][4];
#pragma unroll
    for (int sm = 0; sm < 4; ++sm)
#pragma unroll
      for (int kt = 0; kt < 4; ++kt) {
        int m = mh + sm * 16 + c16;
        int byte = (m * 256 + (kt * 32 + gq * 8) * 2) ^ ((m & 7) << 4);
        af[sm][kt] = __builtin_bit_cast(f16x8, *(const u32x4*)((const char*)Ash + byte));
      }
#pragma unroll
    for (int nt = 0; nt < 4; ++nt)
#pragma unroll
      for (int kt = 0; kt < 4; ++kt) {
        int n = nh + nt * 16 + c16;
        int byte = (n * 256 + (kt * 32 + gq * 8) * 2) ^ ((n & 7) << 4);
        bfr[nt][kt] = __builtin_bit_cast(f16x8, *(const u32x4*)((const char*)Bsh + byte));
      }

    f32x4 acc[4][4];
#pragma unroll
    for (int sm = 0; sm < 4; ++sm)
#pragma unroll
      for (int nt = 0; nt < 4; ++nt) { f32x4 z = {0.f, 0.f, 0.f, 0.f}; acc[sm][nt] = z; }
#pragma unroll
    for (int sm = 0; sm < 4; ++sm)
#pragma unroll
      for (int nt = 0; nt < 4; ++nt)
#pragma unroll
        for (int kt = 0; kt < 4; ++kt)
          acc[sm][nt] = __builtin_amdgcn_mfma_f32_16x16x32_f16(af[sm][kt], bfr[nt][kt], acc[sm][nt], 0, 0, 0);

#pragma unroll
    for (int sm = 0; sm < 4; ++sm)
#pragma unroll
      for (int nt = 0; nt < 4; ++nt) {
        long row = m0 + mh + sm * 16 + gq * 4;
        int gcol = nc * 128 + nh + nt * 16 + c16;
#pragma unroll
        for (int r = 0; r < 4; ++r)
          xg[(size_t)(row + r) * 1024 + gcol] = f2h(acc[sm][nt][r] + bias_v[nt]);
      }
  }
}

// ---------------------------------------------------------------- fused kernel
// 1024 threads. blocks 0-127: lstm chunk c (4 rows, 16 waves, 1 output/lane).
// blocks 128-255: xgemm chunk c+1.
__global__ __launch_bounds__(1024)
void fused_chunk(
    const unsigned short* __restrict__ xgc, const signed char* __restrict__ wq,
    const float* __restrict__ scales, signed char* __restrict__ hst,
    float* __restrict__ cst, float* __restrict__ out, int Tc, int first, int last,
    const float* __restrict__ x, const unsigned short* __restrict__ wih,
    const float* __restrict__ bconv, unsigned short* __restrict__ xgn,
    int t0n, int tclog, int do_x) {
  __shared__ char smem[65536];

  const int tid  = threadIdx.x;
  const int lane = tid & 63;
  const int wv   = tid >> 6;      // 0..15
  const int c16  = lane & 15;
  const int gq   = lane >> 4;     // 0..3

  if (blockIdx.x < 128) {
    // ------------------------------ LSTM: rows 0..3 at M-rows {0,4,8,12}
    signed char (*hb)[1152] = (signed char (*)[1152])smem;  // [buf][4 x 288B]
    const int b0 = blockIdx.x * 4;
    const int col = wv * 16 + c16;          // this lane's single output col
    float cv = cst[(b0 + gq) * 256 + col];  // output row = gq

    const float sw   = scales[0] * (1.0f / 127.0f);
    const float facR = sw * (1.0f / 127.0f);
    const float fac0 = first ? sw * (scales[1] * (1.0f / 127.0f)) : facR;

    // weights: gate g, n = g*256 + col, k = kt*64 + gq*16 -> 64 VGPR total
    i32x4 wf[4][4];
#pragma unroll
    for (int g = 0; g < 4; ++g)
#pragma unroll
      for (int kt = 0; kt < 4; ++kt)
        wf[g][kt] = *(const i32x4*)(wq + (g * 256 + col) * 256 + kt * 64 + gq * 16);
#pragma unroll
    for (int g = 0; g < 4; ++g)
#pragma unroll
      for (int kt = 0; kt < 4; ++kt)
        asm volatile("" : "+v"(wf[g][kt]));

    // init hb[0]: rows 0..3 (stride 288B), cols 0..255
    {
      int row = tid >> 8, cc = tid & 255;
      hb[0][row * 288 + cc] = hst[(b0 + row) * 256 + cc];
    }

    // per-lane xg: [row=gq][t][col*4 + gate], 8 B/lane/step
    const char* pxp = (const char*)xgc +
        (((size_t)(b0 + gq) * Tc) * 1024 + (size_t)col * 4) * 2;

    const bool mrow = (c16 & 3) == 0;  // A-lanes: M-rows 0,4,8,12
    const signed char* hpA = &hb[0][(c16 >> 2) * 288 + gq * 16];  // read buf 0
    const signed char* hpB = &hb[1][(c16 >> 2) * 288 + gq * 16];  // read buf 1
    signed char* hwA = &hb[1][gq * 288 + col];  // write buf 1 (even steps)
    signed char* hwB = &hb[0][gq * 288 + col];  // write buf 0 (odd steps)

    i32x4 af[4];
#pragma unroll
    for (int kt = 0; kt < 4; ++kt) { i32x4 z = {0, 0, 0, 0}; af[kt] = z; }
    const i32x4 zacc = {0, 0, 0, 0};
    int qlast = 0;

    uint2 pxA = *(const uint2*)pxp; pxp += 2048;   // t=0
    uint2 pxB;

    __syncthreads();

#define LSTM_MFMA_CLUSTER(ACC, AF)                                            \
    {                                                                          \
      __builtin_amdgcn_s_setprio(1);                                           \
      const int go_[4] = {2, 0, 1, 3};                                         \
      _Pragma("unroll")                                                        \
      for (int gi_ = 0; gi_ < 4; ++gi_) {                                      \
        const int g = go_[gi_];                                                \
        ACC[g] = __builtin_amdgcn_mfma_i32_16x16x64_i8(AF[0], wf[g][0], zacc, 0, 0, 0); \
        _Pragma("unroll")                                                      \
        for (int kt = 1; kt < 4; ++kt)                                         \
          ACC[g] = __builtin_amdgcn_mfma_i32_16x16x64_i8(AF[kt], wf[g][kt], ACC[g], 0, 0, 0); \
      }                                                                        \
      __builtin_amdgcn_s_setprio(0);                                           \
    }

#define LSTM_EW(ACC, PX, FAC, HW)                                              \
    {                                                                          \
      float xi  = h2f((unsigned short)(PX.x & 0xffff));                        \
      float xf  = h2f((unsigned short)(PX.x >> 16));                           \
      float xgv = h2f((unsigned short)(PX.y & 0xffff));                        \
      float xo  = h2f((unsigned short)(PX.y >> 16));                           \
      float gi = __builtin_fmaf((float)ACC[0][0], FAC, xi);                    \
      float gf = __builtin_fmaf((float)ACC[1][0], FAC, xf);                    \
      float gg = __builtin_fmaf((float)ACC[2][0], FAC, xgv);                   \
      float go = __builtin_fmaf((float)ACC[3][0], FAC, xo);                    \
      cv = fast_sigmoid(gf) * cv + fast_sigmoid(gi) * fast_tanh(gg);           \
      float hn = fast_sigmoid(go) * fast_tanh(cv);                             \
      qlast = (int)rintf(hn * 127.0f);                                         \
      *HW = (signed char)qlast;                                                \
    }

    for (int tt = 0; tt < Tc; tt += 2) {
      // ---------------- even step (read buf0, write buf1)
      pxB = *(const uint2*)pxp; pxp += 2048;   // xg for odd step
      if (mrow) {
        af[0] = *(const i32x4*)(hpA);
        af[1] = *(const i32x4*)(hpA + 64);
        af[2] = *(const i32x4*)(hpA + 128);
        af[3] = *(const i32x4*)(hpA + 192);
      }
      i32x4 accA[4];
      LSTM_MFMA_CLUSTER(accA, af)
      {
        const float facE = (tt == 0) ? fac0 : facR;
        LSTM_EW(accA, pxA, facE, hwA)
      }
      __syncthreads();

      // ---------------- odd step (read buf1, write buf0)
      pxA = *(const uint2*)pxp; pxp += 2048;   // xg for next even step
      if (mrow) {
        af[0] = *(const i32x4*)(hpB);
        af[1] = *(const i32x4*)(hpB + 64);
        af[2] = *(const i32x4*)(hpB + 128);
        af[3] = *(const i32x4*)(hpB + 192);
      }
      i32x4 accB[4];
      LSTM_MFMA_CLUSTER(accB, af)
      LSTM_EW(accB, pxB, facR, hwB)
      __syncthreads();
    }
#undef LSTM_MFMA_CLUSTER
#undef LSTM_EW

    cst[(b0 + gq) * 256 + col] = cv;
    hst[(b0 + gq) * 256 + col] = (signed char)qlast;
    if (last) out[(b0 + gq) * 256 + col] = cv;
  } else if (do_x) {
    // ------------------------------ XGEMM chunk c+1 (1024 thr, 16 waves)
    unsigned short* Ash = (unsigned short*)smem;            // 128x128 f16
    unsigned short* Bsh = (unsigned short*)(smem + 32768);  // 128x128 f16
    const int tcm    = (1 << tclog) - 1;
    const int ntiles = Tc << 2;            // (512*Tc)/128
    const int wm = wv >> 2, wn = wv & 3;   // 4x4 wave grid
    const int mh = wm * 32, nh = wn * 32;

    for (int rt = (int)blockIdx.x - 128; rt < ntiles; rt += 128) {
      const long m0 = (long)rt * 128;
      __syncthreads();  // previous tile's readers done before re-staging

#pragma unroll
      for (int i = 0; i < 4; ++i) {
        int fidx = (i * 1024 + tid) * 4;
        int row = fidx >> 7, k = fidx & 127;
        long cr = m0 + row;
        long b  = cr >> tclog;
        long tl = cr & tcm;
        f32x4 v = *(const f32x4*)(x + ((size_t)b * 512 + t0n + tl) * 128 + k);
        ushort4 pk;
        pk.x = f2h(v[0]); pk.y = f2h(v[1]); pk.z = f2h(v[2]); pk.w = f2h(v[3]);
        int byte = (row * 256 + k * 2) ^ ((row & 7) << 4);
        *(ushort4*)((char*)Ash + byte) = pk;
      }

      for (int nc = 0; nc < 8; ++nc) {
        __syncthreads();
        {
          const char* wb = (const char*)(wih + nc * 128 * 128);
#pragma unroll
          for (int i = 0; i < 2; ++i) {
            int idx16 = i * 1024 + tid;
            int row = idx16 >> 4, ch = idx16 & 15;
            int srcoff = row * 256 + ((ch * 16) ^ ((row & 7) << 4));
            u32x4 v = *(const u32x4*)(wb + srcoff);
            *(u32x4*)((char*)Bsh + idx16 * 16) = v;
          }
        }
        __syncthreads();

        float bias_v[2];
#pragma unroll
        for (int nt = 0; nt < 2; ++nt)
          bias_v[nt] = bconv[nc * 128 + nh + nt * 16 + c16];

        f16x8 af[2][4], bfr[2][4];
#pragma unroll
        for (int sm = 0; sm < 2; ++sm)
#pragma unroll
          for (int kt = 0; kt < 4; ++kt) {
            int m = mh + sm * 16 + c16;
            int byte = (m * 256 + (kt * 32 + gq * 8) * 2) ^ ((m & 7) << 4);
            af[sm][kt] = __builtin_bit_cast(f16x8, *(const u32x4*)((const char*)Ash + byte));
          }
#pragma unroll
        for (int nt = 0; nt < 2; ++nt)
#pragma unroll
          for (int kt = 0; kt < 4; ++kt) {
            int n = nh + nt * 16 + c16;
            int byte = (n * 256 + (kt * 32 + gq * 8) * 2) ^ ((n & 7) << 4);
            bfr[nt][kt] = __builtin_bit_cast(f16x8, *(const u32x4*)((const char*)Bsh + byte));
          }

        f32x4 acc[2][2];
#pragma unroll
        for (int sm = 0; sm < 2; ++sm)
#pragma unroll
          for (int nt = 0; nt < 2; ++nt) { f32x4 z = {0.f, 0.f, 0.f, 0.f}; acc[sm][nt] = z; }
#pragma unroll
        for (int sm = 0; sm < 2; ++sm)
#pragma unroll
          for (int nt = 0; nt < 2; ++nt)
#pragma unroll
            for (int kt = 0; kt < 4; ++kt)
              acc[sm][nt] = __builtin_amdgcn_mfma_f32_16x16x32_f16(af[sm][kt], bfr[nt][kt], acc[sm][nt], 0, 0, 0);

#pragma unroll
        for (int sm = 0; sm < 2; ++sm)
#pragma unroll
          for (int nt = 0; nt < 2; ++nt) {
            long row = m0 + mh + sm * 16 + gq * 4;
            int gcol = nc * 128 + nh + nt * 16 + c16;
#pragma unroll
            for (int r = 0; r < 4; ++r)
              xgn[(size_t)(row + r) * 1024 + gcol] = f2h(acc[sm][nt][r] + bias_v[nt]);
          }
      }
    }
  }
}

// ---------------------------------------------------------------- launch
extern "C" void kernel_launch(void* const* d_in, const int* in_sizes, int n_in,
                              void* d_out, int out_size, void* d_ws, size_t ws_size,
                              hipStream_t stream) {
  const float* x   = (const float*)d_in[0];
  const float* h0  = (const float*)d_in[1];
  const float* c0  = (const float*)d_in[2];
  const float* wih = (const float*)d_in[3];
  const float* whh = (const float*)d_in[4];
  const float* bih = (const float*)d_in[5];
  const float* bhh = (const float*)d_in[6];
  float* out = (float*)d_out;

  const size_t fixed = 262144u /*wih f16*/ + 262144u /*wq*/ + 131072u /*hst*/
                     + 524288u /*cst*/ + 4096u /*bconv*/ + 1024u /*scales*/;
  int tc = 128;  // ws_size caps 2 xg buffers at 2x134MB -> tc=128, NC=4
  while (tc > 4 && 2u * (size_t)512 * tc * 2048 + fixed > ws_size) tc >>= 1;
  int tclog = 31 - __builtin_clz((unsigned)tc);
  size_t bufsz = (size_t)512 * tc * 2048;

  char* ws = (char*)d_ws;
  unsigned short* xgb0  = (unsigned short*)ws;
  unsigned short* xgb1  = (unsigned short*)(ws + bufsz);
  size_t off = 2u * bufsz;
  unsigned short* wih_h = (unsigned short*)(ws + off);  off += 262144u;
  signed char*    wqb   = (signed char*)(ws + off);     off += 262144u;
  signed char*    hst   = (signed char*)(ws + off);     off += 131072u;
  float*          cst   = (float*)(ws + off);           off += 524288u;
  float*          bcv   = (float*)(ws + off);           off += 4096u;
  float*          scl   = (float*)(ws + off);

  prep1<<<320, 256, 0, stream>>>(whh, h0, wih, bih, bhh, scl, wih_h, bcv);
  prep2<<<256, 256, 0, stream>>>(whh, h0, c0, scl, wqb, hst, cst);

  // prologue: xgemm for chunk 0 (full chip)
  xgemm<<<4 * tc, 256, 0, stream>>>(x, wih_h, bcv, xgb0, 0, tclog);

  int NC = 512 / tc;
  for (int c = 0; c < NC; ++c) {
    unsigned short* cur = (c & 1) ? xgb1 : xgb0;
    unsigned short* nxt = (c & 1) ? xgb0 : xgb1;
    int do_x = (c + 1 < NC) ? 1 : 0;
    fused_chunk<<<256, 1024, 0, stream>>>(
        cur, wqb, scl, hst, cst, out, tc, (c == 0) ? 1 : 0, (c == NC - 1) ? 1 : 0,
        x, wih_h, bcv, nxt, (c + 1) * tc, tclog, do_x);
  }
}